// Round 1
// 1726.945 us; speedup vs baseline: 1.1416x; 1.1416x over previous
//
#include <hip/hip_runtime.h>
#include <hip/hip_bf16.h>
#include <math.h>

#define NLEV 12
#define B_LINES 4096
#define P_PTS 1000
#define FP8_SCALE 65536.0f
#define FP8_ISCALE (1.0f / 65536.0f)

typedef unsigned short ushort_t;
typedef __attribute__((ext_vector_type(8))) short short8_t;   // 8 bf16 (4 VGPRs)
typedef __attribute__((ext_vector_type(4))) float f32x4;

// Per-level table layout, mirrors _level_specs() exactly.
struct LevelSpec {
    unsigned off;    // entry offset into table (rows of 2 features)
    unsigned mask;   // params-1 (power-of-2 for hash levels)
    float    scale;  // BASE_RES * f^l - 1
    unsigned R;      // res + 1 (dense stride base)
};
struct Specs { LevelSpec L[NLEV]; };

static unsigned compute_specs(int D, Specs* sp) {
    double f = pow(8192.0 / 16.0, 1.0 / 11.0);
    unsigned offset = 0;
    for (int l = 0; l < NLEV; ++l) {
        double scale = 16.0 * pow(f, (double)l) - 1.0;
        int res = (int)ceil(scale) + 1;
        unsigned long long dense = 1ull;
        for (int d = 0; d < D; ++d) dense *= (unsigned long long)(res + 1);
        unsigned long long params = dense > (1ull << 21) ? (1ull << 21) : dense;
        params = ((params + 7ull) / 8ull) * 8ull;
        sp->L[l].off   = offset;
        sp->L[l].mask  = (unsigned)params - 1u;
        sp->L[l].scale = (float)scale;
        sp->L[l].R     = (unsigned)(res + 1);
        offset += (unsigned)params;
    }
    return offset;  // total entries
}

// ---------------------------------------------------------------------------

__device__ __forceinline__ float block_reduce_256(float v) {
    __shared__ float red[256];
    int tid = threadIdx.x;
    red[tid] = v;
    __syncthreads();
    #pragma unroll
    for (int s = 128; s >= 1; s >>= 1) {
        if (tid < s) red[tid] += red[tid + s];
        __syncthreads();
    }
    return red[0];
}

__device__ __forceinline__ unsigned short f32_to_bf16_bits(float f) {
    unsigned u = __float_as_uint(f);
    unsigned r = (u + 0x7fffu + ((u >> 16) & 1u)) >> 16;   // RNE
    return (unsigned short)r;
}

// MLP 24 -> 64(relu) -> 1; weights wave-uniform -> s_load + v_fmac.
// (still used by the fallback mono path and conf path)
__device__ __forceinline__ float mlp_24_64_1(const float feat[24],
        const float* __restrict__ w1, const float* __restrict__ b1,
        const float* __restrict__ w2, const float* __restrict__ b2) {
    float o = b2[0];
    #pragma unroll
    for (int half = 0; half < 2; ++half) {
        float h[32];
        #pragma unroll
        for (int j = 0; j < 32; ++j) h[j] = b1[half * 32 + j];
        #pragma unroll
        for (int k = 0; k < 24; ++k) {
            float fv = feat[k];
            #pragma unroll
            for (int j = 0; j < 32; ++j)
                h[j] = fmaf(fv, w1[k * 64 + half * 32 + j], h[j]);
        }
        #pragma unroll
        for (int j = 0; j < 32; ++j)
            o = fmaf(fmaxf(h[j], 0.f), w2[half * 32 + j], o);
    }
    return o;
}

// ---------------------------------------------------------------------------
// fp8 table conversion: one row (2 features) -> 2 bytes, scaled by 2^16.
__global__ void __launch_bounds__(256) convert_kernel(
        const float2* __restrict__ in, ushort_t* __restrict__ out, int n) {
    int i = blockIdx.x * 256 + threadIdx.x;
    if (i >= n) return;
    float2 v = in[i];
    int p = __builtin_amdgcn_cvt_pk_fp8_f32(v.x * FP8_SCALE, v.y * FP8_SCALE,
                                            0, false);
    out[i] = (ushort_t)(p & 0xffff);
}

// Dense levels 0..3 (combined fp8 footprint ~1.8 MB: L2-resident).
__global__ void __launch_bounds__(256) enc_dense_kernel(
        const float* __restrict__ pts, int pbase, int npts,
        const ushort_t* __restrict__ tabq,
        __hip_bfloat162* __restrict__ feats,   // 12 slabs of npts
        Specs sp) {
    int i = blockIdx.x * 256 + threadIdx.x;
    if (i >= npts) return;
    int gp = pbase + i;
    float x0 = (pts[3 * gp + 0] + 1.f) * 0.5f;
    float x1 = (pts[3 * gp + 1] + 1.f) * 0.5f;
    float x2 = (pts[3 * gp + 2] + 1.f) * 0.5f;
    #pragma unroll
    for (int l = 0; l < 4; ++l) {
        const LevelSpec L = sp.L[l];
        float p0 = x0 * L.scale + 0.5f;
        float p1 = x1 * L.scale + 0.5f;
        float p2 = x2 * L.scale + 0.5f;
        float f0 = floorf(p0), f1 = floorf(p1), f2 = floorf(p2);
        float r0 = p0 - f0, r1 = p1 - f1, r2 = p2 - f2;
        float u0 = 1.f - r0, u1 = 1.f - r1, u2 = 1.f - r2;
        unsigned g0 = (unsigned)f0, g1 = (unsigned)f1, g2 = (unsigned)f2;
        const ushort_t* __restrict__ base = tabq + L.off;
        unsigned R = L.R, R2 = R * R;
        unsigned y0 = g1 * R, y1 = y0 + R;
        unsigned z0 = g2 * R2, z1 = z0 + R2;
        int t[8];
        #pragma unroll
        for (int c = 0; c < 8; ++c) {
            unsigned idx = (g0 + ((c & 1) ? 1u : 0u))
                         + ((c & 2) ? y1 : y0) + ((c & 4) ? z1 : z0);
            t[c] = (int)base[idx];
        }
        float a0 = 0.f, a1 = 0.f;
        #pragma unroll
        for (int c = 0; c < 8; ++c) {
            float w = ((c & 1) ? r0 : u0) * ((c & 2) ? r1 : u1)
                    * ((c & 4) ? r2 : u2);
            a0 = fmaf(w, __builtin_amdgcn_cvt_f32_fp8(t[c], 0), a0);
            a1 = fmaf(w, __builtin_amdgcn_cvt_f32_fp8(t[c], 1), a1);
        }
        __hip_bfloat162 o;
        o.x = __float2bfloat16(a0 * FP8_ISCALE);
        o.y = __float2bfloat16(a1 * FP8_ISCALE);
        feats[(size_t)l * npts + i] = o;
    }
}

// One hash level per launch: the 4 MB fp8 level table fits each XCD's L2.
__global__ void __launch_bounds__(256) enc_hash_kernel(
        const float* __restrict__ pts, int pbase, int npts,
        const ushort_t* __restrict__ tabq, LevelSpec L,
        __hip_bfloat162* __restrict__ featsl) {   // this level's slab
    int i = blockIdx.x * 256 + threadIdx.x;
    if (i >= npts) return;
    int gp = pbase + i;
    float x0 = (pts[3 * gp + 0] + 1.f) * 0.5f;
    float x1 = (pts[3 * gp + 1] + 1.f) * 0.5f;
    float x2 = (pts[3 * gp + 2] + 1.f) * 0.5f;
    float p0 = x0 * L.scale + 0.5f;
    float p1 = x1 * L.scale + 0.5f;
    float p2 = x2 * L.scale + 0.5f;
    float f0 = floorf(p0), f1 = floorf(p1), f2 = floorf(p2);
    float r0 = p0 - f0, r1 = p1 - f1, r2 = p2 - f2;
    float u0 = 1.f - r0, u1 = 1.f - r1, u2 = 1.f - r2;
    unsigned g0 = (unsigned)f0, g1 = (unsigned)f1, g2 = (unsigned)f2;
    const ushort_t* __restrict__ base = tabq + L.off;
    unsigned y0 = g1 * 2654435761u, y1 = y0 + 2654435761u;
    unsigned z0 = g2 * 805459861u,  z1 = z0 + 805459861u;
    unsigned m = L.mask;
    int t[8];
    #pragma unroll
    for (int c = 0; c < 8; ++c) {
        unsigned h = (g0 + ((c & 1) ? 1u : 0u))
                   ^ ((c & 2) ? y1 : y0) ^ ((c & 4) ? z1 : z0);
        t[c] = (int)base[h & m];
    }
    float a0 = 0.f, a1 = 0.f;
    #pragma unroll
    for (int c = 0; c < 8; ++c) {
        float w = ((c & 1) ? r0 : u0) * ((c & 2) ? r1 : u1)
                * ((c & 4) ? r2 : u2);
        a0 = fmaf(w, __builtin_amdgcn_cvt_f32_fp8(t[c], 0), a0);
        a1 = fmaf(w, __builtin_amdgcn_cvt_f32_fp8(t[c], 1), a1);
    }
    __hip_bfloat162 o;
    o.x = __float2bfloat16(a0 * FP8_ISCALE);
    o.y = __float2bfloat16(a1 * FP8_ISCALE);
    featsl[i] = o;
}

// ---------------------------------------------------------------------------
// MFMA per-line MLP + weighted |op-gt| sum. One block (4 waves) per line.
// A = feats (16 pts x K32, features 24..31 zero), B = W1 bf16 (K32 x 16),
// 4 n-blocks cover the 64 hidden units. b1 is preloaded into the accumulator.
// Layouts (gfx950 16x16x32 bf16):
//   A: lane l holds A[l&15][(l>>4)*8 + i]           (i = 0..7)
//   B: lane l holds B[(l>>4)*8 + i][l&15]
//   D: lane l holds D[(l>>4)*4 + r][l&15]           (r = 0..3)
__global__ void __launch_bounds__(256) mlp_loss_mfma_kernel(
        const unsigned* __restrict__ feats, int npts,
        const float* __restrict__ gt, int line0,
        const float* __restrict__ w1, const float* __restrict__ b1,
        const float* __restrict__ w2, const float* __restrict__ b2,
        float* __restrict__ S) {
    const int line_local = blockIdx.x;
    const int tid  = threadIdx.x;
    const int wave = tid >> 6;
    const int lane = tid & 63;
    const int c = lane & 15;      // hidden col within 16 / A point row
    const int g = lane >> 4;      // k-group (0..3)

    // Loop-invariant B fragments: W1[k][64] f32 -> bf16, K padded 24->32.
    short8_t bfrag[4];
    #pragma unroll
    for (int nb = 0; nb < 4; ++nb) {
        #pragma unroll
        for (int i = 0; i < 8; ++i) {
            int k = g * 8 + i;
            float v = (k < 24) ? w1[k * 64 + nb * 16 + c] : 0.f;
            bfrag[nb][i] = (short)f32_to_bf16_bits(v);
        }
    }
    float b1v[4], w2v[4];
    #pragma unroll
    for (int nb = 0; nb < 4; ++nb) {
        b1v[nb] = b1[nb * 16 + c];
        w2v[nb] = w2[nb * 16 + c];
    }
    const float b2v = b2[0];

    const size_t lbase = (size_t)line_local * P_PTS;
    float lsum = 0.f;

    // 16 iterations x 4 waves x 16 points = 1024 >= 1000 (tail masked).
    for (int it = 0; it < 16; ++it) {
        const int base16 = it * 64 + wave * 16;
        // --- A fragment: point row = c, k = g*8 + i (2 bf16 per level slab)
        int prow = base16 + c;
        int pcl  = prow < P_PTS ? prow : P_PTS - 1;
        size_t pidx = lbase + (size_t)pcl;
        union { unsigned u[4]; short8_t v; } a;
        if (g < 3) {
            #pragma unroll
            for (int s = 0; s < 4; ++s)
                a.u[s] = feats[(size_t)(g * 4 + s) * npts + pidx];
        } else {
            a.u[0] = 0u; a.u[1] = 0u; a.u[2] = 0u; a.u[3] = 0u;
        }
        // --- layer 1: 4 MFMAs, accumulator seeded with b1
        f32x4 acc[4];
        #pragma unroll
        for (int nb = 0; nb < 4; ++nb) {
            f32x4 ci = {b1v[nb], b1v[nb], b1v[nb], b1v[nb]};
            acc[nb] = __builtin_amdgcn_mfma_f32_16x16x32_bf16(
                a.v, bfrag[nb], ci, 0, 0, 0);
        }
        // --- layer 2: relu + dot with w2, reduce across the 16-lane group
        float part[4];
        #pragma unroll
        for (int r = 0; r < 4; ++r) {
            float s = fmaxf(acc[0][r], 0.f) * w2v[0];
            s = fmaf(fmaxf(acc[1][r], 0.f), w2v[1], s);
            s = fmaf(fmaxf(acc[2][r], 0.f), w2v[2], s);
            s = fmaf(fmaxf(acc[3][r], 0.f), w2v[3], s);
            part[r] = s;
        }
        #pragma unroll
        for (int off = 1; off < 16; off <<= 1) {
            #pragma unroll
            for (int r = 0; r < 4; ++r)
                part[r] += __shfl_xor(part[r], off);
        }
        // lane c<4 owns point p = base16 + g*4 + c (exactly one lane/point)
        if (c < 4) {
            int p = base16 + g * 4 + c;
            if (p < P_PTS) {
                float op = part[c] + b2v;
                float gv = gt[(size_t)(line0 + line_local) * P_PTS + p];
                float cw = (p < 500) ? (float)(4.0 / 3.0) : (float)(2.0 / 3.0);
                lsum += fabsf(op - gv) * cw;
            }
        }
    }
    float tot = block_reduce_256(lsum);
    if (tid == 0) S[line0 + line_local] = tot;
}

// ---------------------------------------------------------------------------
// Fallback monolithic opacity kernel (R1 structure) if ws is too small.
__global__ void __launch_bounds__(256) opacity_mono_kernel(
        const float* __restrict__ pts, const float* __restrict__ gt,
        const float2* __restrict__ tab,
        const float* __restrict__ w1, const float* __restrict__ b1,
        const float* __restrict__ w2, const float* __restrict__ b2,
        float* __restrict__ S, Specs sp) {
    const int b = blockIdx.x;
    const int tid = threadIdx.x;
    float lsum = 0.f;
    for (int p = tid; p < P_PTS; p += 256) {
        const int i = b * P_PTS + p;
        float x0 = (pts[3 * i + 0] + 1.f) * 0.5f;
        float x1 = (pts[3 * i + 1] + 1.f) * 0.5f;
        float x2 = (pts[3 * i + 2] + 1.f) * 0.5f;
        float feat[24];
        #pragma unroll
        for (int l = 0; l < NLEV; ++l) {
            const LevelSpec L = sp.L[l];
            float p0 = x0 * L.scale + 0.5f;
            float p1 = x1 * L.scale + 0.5f;
            float p2 = x2 * L.scale + 0.5f;
            float f0 = floorf(p0), f1 = floorf(p1), f2 = floorf(p2);
            float r0 = p0 - f0, r1 = p1 - f1, r2 = p2 - f2;
            float u0 = 1.f - r0, u1 = 1.f - r1, u2 = 1.f - r2;
            unsigned g0 = (unsigned)f0, g1 = (unsigned)f1, g2 = (unsigned)f2;
            float a0 = 0.f, a1 = 0.f;
            if (l >= 4) {
                unsigned y0 = g1 * 2654435761u, y1 = y0 + 2654435761u;
                unsigned z0 = g2 * 805459861u,  z1 = z0 + 805459861u;
                unsigned m = L.mask;
                #pragma unroll
                for (int c = 0; c < 8; ++c) {
                    unsigned h = (g0 + ((c & 1) ? 1u : 0u))
                               ^ ((c & 2) ? y1 : y0) ^ ((c & 4) ? z1 : z0);
                    float2 t = tab[L.off + (h & m)];
                    float w = ((c & 1) ? r0 : u0) * ((c & 2) ? r1 : u1)
                            * ((c & 4) ? r2 : u2);
                    a0 = fmaf(w, t.x, a0); a1 = fmaf(w, t.y, a1);
                }
            } else {
                unsigned R = L.R, R2 = R * R;
                unsigned y0 = g1 * R, y1 = y0 + R;
                unsigned z0 = g2 * R2, z1 = z0 + R2;
                #pragma unroll
                for (int c = 0; c < 8; ++c) {
                    unsigned idx = (g0 + ((c & 1) ? 1u : 0u))
                                 + ((c & 2) ? y1 : y0) + ((c & 4) ? z1 : z0);
                    float2 t = tab[L.off + idx];
                    float w = ((c & 1) ? r0 : u0) * ((c & 2) ? r1 : u1)
                            * ((c & 4) ? r2 : u2);
                    a0 = fmaf(w, t.x, a0); a1 = fmaf(w, t.y, a1);
                }
            }
            feat[2 * l] = a0; feat[2 * l + 1] = a1;
        }
        float op = mlp_24_64_1(feat, w1, b1, w2, b2);
        float cw = (p < 500) ? (float)(4.0 / 3.0) : (float)(2.0 / 3.0);
        lsum += fabsf(op - gt[i]) * cw;
    }
    float tot = block_reduce_256(lsum);
    if (tid == 0) S[b] = tot;
}

// Confidence (D=2, tiny) + final reduction: unchanged (f32 table).
__global__ void __launch_bounds__(256) conf_kernel(
        const float* __restrict__ line, const float2* __restrict__ tab,
        const float* __restrict__ w1, const float* __restrict__ b1,
        const float* __restrict__ w2, const float* __restrict__ b2,
        const float* __restrict__ S, float* __restrict__ partial, Specs sp) {
    const int b = blockIdx.x * 256 + threadIdx.x;
    float x0 = (line[2 * b + 0] + 1.f) * 0.5f;
    float x1 = (line[2 * b + 1] + 1.f) * 0.5f;
    float feat[24];
    #pragma unroll
    for (int l = 0; l < NLEV; ++l) {
        const unsigned off = sp.L[l].off;
        const float scale = sp.L[l].scale;
        float p0 = x0 * scale + 0.5f;
        float p1 = x1 * scale + 0.5f;
        float f0 = floorf(p0), f1 = floorf(p1);
        float r0 = p0 - f0, r1 = p1 - f1;
        float u0 = 1.f - r0, u1 = 1.f - r1;
        unsigned g0 = (unsigned)f0, g1 = (unsigned)f1;
        unsigned idx0, idx1, idx2, idx3;
        if (l >= 8) {
            const unsigned mask = sp.L[l].mask;
            unsigned a1 = g1 * 2654435761u, bb1 = a1 + 2654435761u;
            idx0 = (g0 ^ a1) & mask;
            idx1 = ((g0 + 1u) ^ a1) & mask;
            idx2 = (g0 ^ bb1) & mask;
            idx3 = ((g0 + 1u) ^ bb1) & mask;
        } else {
            const unsigned R = sp.L[l].R;
            unsigned a1 = g1 * R, bb1 = a1 + R;
            idx0 = g0 + a1; idx1 = g0 + 1u + a1;
            idx2 = g0 + bb1; idx3 = g0 + 1u + bb1;
        }
        float2 t0 = tab[off + idx0], t1 = tab[off + idx1];
        float2 t2 = tab[off + idx2], t3 = tab[off + idx3];
        float w0 = u0 * u1, w1c = r0 * u1, w2c = u0 * r1, w3 = r0 * r1;
        feat[2 * l]     = w0 * t0.x + w1c * t1.x + w2c * t2.x + w3 * t3.x;
        feat[2 * l + 1] = w0 * t0.y + w1c * t1.y + w2c * t2.y + w3 * t3.y;
    }
    float conf = mlp_24_64_1(feat, w1, b1, w2, b2);
    float term = expf(-conf) * (S[b] * (1.0f / (float)P_PTS)) + conf;
    float tot = block_reduce_256(term);
    if (threadIdx.x == 0) partial[blockIdx.x] = tot;
}

__global__ void final_kernel(const float* __restrict__ partial,
                             float* __restrict__ out) {
    if (threadIdx.x == 0) {
        float s = 0.f;
        for (int i = 0; i < 16; ++i) s += partial[i];
        out[0] = s * (1.0f / (float)B_LINES);
    }
}

// ---------------------------------------------------------------------------

extern "C" void kernel_launch(void* const* d_in, const int* in_sizes, int n_in,
                              void* d_out, int out_size, void* d_ws, size_t ws_size,
                              hipStream_t stream) {
    const float* line    = (const float*)d_in[0];
    const float* pts     = (const float*)d_in[1];
    const float* gt      = (const float*)d_in[2];
    const float* table_c = (const float*)d_in[3];
    const float* w1_c    = (const float*)d_in[4];
    const float* b1_c    = (const float*)d_in[5];
    const float* w2_c    = (const float*)d_in[6];
    const float* b2_c    = (const float*)d_in[7];
    const float* table_o = (const float*)d_in[8];
    const float* w1_o    = (const float*)d_in[9];
    const float* b1_o    = (const float*)d_in[10];
    const float* w2_o    = (const float*)d_in[11];
    const float* b2_o    = (const float*)d_in[12];
    (void)in_sizes; (void)n_in; (void)out_size;

    Specs sp3, sp2;
    unsigned tot3 = compute_specs(3, &sp3);
    compute_specs(2, &sp2);

    // ws layout: [fp8 table][S 4096][partial 16][feat slabs]
    size_t tabB = (((size_t)tot3 * 2) + 255) & ~(size_t)255;
    size_t head = tabB + (size_t)B_LINES * 4 + 64;
    head = (head + 63) & ~(size_t)63;
    long max_lines = 0;
    if (ws_size > head + 64)
        max_lines = (long)((ws_size - head - 64) / ((size_t)P_PTS * 12 * 4));

    float* S       = (float*)((char*)d_ws + tabB);
    float* partial = S + B_LINES;

    if (max_lines >= 64) {
        // Phased fp8 path.
        ushort_t* tabq = (ushort_t*)d_ws;
        __hip_bfloat162* featbuf = (__hip_bfloat162*)((char*)d_ws + head);

        int chunk_lines = (int)(max_lines < B_LINES ? max_lines : B_LINES);
        // Cap so featbuf (48 KB/line) stays L3-resident between enc and mlp.
        if (chunk_lines > 1024) chunk_lines = 1024;
        int nch = (B_LINES + chunk_lines - 1) / chunk_lines;

        convert_kernel<<<((int)tot3 + 255) / 256, 256, 0, stream>>>(
            (const float2*)table_o, tabq, (int)tot3);

        for (int ch = 0; ch < nch; ++ch) {
            int line0 = ch * chunk_lines;
            int lines = B_LINES - line0 < chunk_lines ? B_LINES - line0
                                                      : chunk_lines;
            int npts = lines * P_PTS;
            int pbase = line0 * P_PTS;
            int grid = (npts + 255) / 256;
            enc_dense_kernel<<<grid, 256, 0, stream>>>(
                pts, pbase, npts, tabq, featbuf, sp3);
            for (int l = 4; l < NLEV; ++l)
                enc_hash_kernel<<<grid, 256, 0, stream>>>(
                    pts, pbase, npts, tabq, sp3.L[l],
                    featbuf + (size_t)l * npts);
            mlp_loss_mfma_kernel<<<lines, 256, 0, stream>>>(
                (const unsigned*)featbuf, npts, gt, line0,
                w1_o, b1_o, w2_o, b2_o, S);
        }
    } else {
        // Fallback: monolithic f32 path (needs only S+partial in ws).
        opacity_mono_kernel<<<B_LINES, 256, 0, stream>>>(
            pts, gt, (const float2*)table_o, w1_o, b1_o, w2_o, b2_o, S, sp3);
    }

    conf_kernel<<<16, 256, 0, stream>>>(
        line, (const float2*)table_c, w1_c, b1_c, w2_c, b2_c, S, partial, sp2);
    final_kernel<<<1, 64, 0, stream>>>(partial, (float*)d_out);
}

// Round 2
// 1577.081 us; speedup vs baseline: 1.2501x; 1.0950x over previous
//
#include <hip/hip_runtime.h>
#include <hip/hip_bf16.h>
#include <math.h>

#define NLEV 12
#define B_LINES 4096
#define P_PTS 1000
#define FP8_SCALE 65536.0f
#define FP8_ISCALE (1.0f / 65536.0f)

typedef unsigned short ushort_t;
typedef __attribute__((ext_vector_type(8))) short short8_t;   // 8 bf16 (4 VGPRs)
typedef __attribute__((ext_vector_type(4))) float f32x4;

// Per-level table layout, mirrors _level_specs() exactly.
struct LevelSpec {
    unsigned off;    // entry offset into table (rows of 2 features)
    unsigned mask;   // params-1 (power-of-2 for hash levels)
    float    scale;  // BASE_RES * f^l - 1
    unsigned R;      // res + 1 (dense stride base)
};
struct Specs { LevelSpec L[NLEV]; };
struct HashScales { float s[8]; };   // scales for levels 4..11

static unsigned compute_specs(int D, Specs* sp) {
    double f = pow(8192.0 / 16.0, 1.0 / 11.0);
    unsigned offset = 0;
    for (int l = 0; l < NLEV; ++l) {
        double scale = 16.0 * pow(f, (double)l) - 1.0;
        int res = (int)ceil(scale) + 1;
        unsigned long long dense = 1ull;
        for (int d = 0; d < D; ++d) dense *= (unsigned long long)(res + 1);
        unsigned long long params = dense > (1ull << 21) ? (1ull << 21) : dense;
        params = ((params + 7ull) / 8ull) * 8ull;
        sp->L[l].off   = offset;
        sp->L[l].mask  = (unsigned)params - 1u;
        sp->L[l].scale = (float)scale;
        sp->L[l].R     = (unsigned)(res + 1);
        offset += (unsigned)params;
    }
    return offset;  // total entries
}

// ---------------------------------------------------------------------------

__device__ __forceinline__ float block_reduce_256(float v) {
    __shared__ float red[256];
    int tid = threadIdx.x;
    red[tid] = v;
    __syncthreads();
    #pragma unroll
    for (int s = 128; s >= 1; s >>= 1) {
        if (tid < s) red[tid] += red[tid + s];
        __syncthreads();
    }
    return red[0];
}

__device__ __forceinline__ unsigned short f32_to_bf16_bits(float f) {
    unsigned u = __float_as_uint(f);
    unsigned r = (u + 0x7fffu + ((u >> 16) & 1u)) >> 16;   // RNE
    return (unsigned short)r;
}

// MLP 24 -> 64(relu) -> 1; weights wave-uniform -> s_load + v_fmac.
// (used by the fallback mono path and conf path)
__device__ __forceinline__ float mlp_24_64_1(const float feat[24],
        const float* __restrict__ w1, const float* __restrict__ b1,
        const float* __restrict__ w2, const float* __restrict__ b2) {
    float o = b2[0];
    #pragma unroll
    for (int half = 0; half < 2; ++half) {
        float h[32];
        #pragma unroll
        for (int j = 0; j < 32; ++j) h[j] = b1[half * 32 + j];
        #pragma unroll
        for (int k = 0; k < 24; ++k) {
            float fv = feat[k];
            #pragma unroll
            for (int j = 0; j < 32; ++j)
                h[j] = fmaf(fv, w1[k * 64 + half * 32 + j], h[j]);
        }
        #pragma unroll
        for (int j = 0; j < 32; ++j)
            o = fmaf(fmaxf(h[j], 0.f), w2[half * 32 + j], o);
    }
    return o;
}

// ---------------------------------------------------------------------------
// fp8 table conversion: one row (2 features) -> 2 bytes, scaled by 2^16.
__global__ void __launch_bounds__(256) convert_kernel(
        const float2* __restrict__ in, ushort_t* __restrict__ out, int n) {
    int i = blockIdx.x * 256 + threadIdx.x;
    if (i >= n) return;
    float2 v = in[i];
    int p = __builtin_amdgcn_cvt_pk_fp8_f32(v.x * FP8_SCALE, v.y * FP8_SCALE,
                                            0, false);
    out[i] = (ushort_t)(p & 0xffff);
}

// Dense levels 0..3 (combined fp8 footprint ~1.8 MB: L2-resident).
__global__ void __launch_bounds__(256) enc_dense_kernel(
        const float* __restrict__ pts, int pbase, int npts,
        const ushort_t* __restrict__ tabq,
        __hip_bfloat162* __restrict__ feats,   // 12 slabs of npts
        Specs sp) {
    int i = blockIdx.x * 256 + threadIdx.x;
    if (i >= npts) return;
    int gp = pbase + i;
    float x0 = (pts[3 * gp + 0] + 1.f) * 0.5f;
    float x1 = (pts[3 * gp + 1] + 1.f) * 0.5f;
    float x2 = (pts[3 * gp + 2] + 1.f) * 0.5f;
    #pragma unroll
    for (int l = 0; l < 4; ++l) {
        const LevelSpec L = sp.L[l];
        float p0 = x0 * L.scale + 0.5f;
        float p1 = x1 * L.scale + 0.5f;
        float p2 = x2 * L.scale + 0.5f;
        float f0 = floorf(p0), f1 = floorf(p1), f2 = floorf(p2);
        float r0 = p0 - f0, r1 = p1 - f1, r2 = p2 - f2;
        float u0 = 1.f - r0, u1 = 1.f - r1, u2 = 1.f - r2;
        unsigned g0 = (unsigned)f0, g1 = (unsigned)f1, g2 = (unsigned)f2;
        const ushort_t* __restrict__ base = tabq + L.off;
        unsigned R = L.R, R2 = R * R;
        unsigned y0 = g1 * R, y1 = y0 + R;
        unsigned z0 = g2 * R2, z1 = z0 + R2;
        int t[8];
        #pragma unroll
        for (int c = 0; c < 8; ++c) {
            unsigned idx = (g0 + ((c & 1) ? 1u : 0u))
                         + ((c & 2) ? y1 : y0) + ((c & 4) ? z1 : z0);
            t[c] = (int)base[idx];
        }
        float a0 = 0.f, a1 = 0.f;
        #pragma unroll
        for (int c = 0; c < 8; ++c) {
            float w = ((c & 1) ? r0 : u0) * ((c & 2) ? r1 : u1)
                    * ((c & 4) ? r2 : u2);
            a0 = fmaf(w, __builtin_amdgcn_cvt_f32_fp8(t[c], 0), a0);
            a1 = fmaf(w, __builtin_amdgcn_cvt_f32_fp8(t[c], 1), a1);
        }
        __hip_bfloat162 o;
        o.x = __float2bfloat16(a0 * FP8_ISCALE);
        o.y = __float2bfloat16(a1 * FP8_ISCALE);
        feats[(size_t)l * npts + i] = o;
    }
}

// All 8 hash levels in ONE launch, XCD-pinned: level = blockIdx & 7, so with
// round-robin block->XCD dispatch each XCD's 4 MB L2 holds exactly ONE level's
// 4 MB fp8 table for the whole phase (levels 4..11 all have 2^21 entries,
// contiguous at hash_off0 + lev*2^21; mask = 2^21-1 for all).
__global__ void __launch_bounds__(256) enc_hash_all_kernel(
        const float* __restrict__ pts, int pbase, int npts,
        const ushort_t* __restrict__ tabq, unsigned hash_off0,
        HashScales hs,
        __hip_bfloat162* __restrict__ feats) {   // slab base (level 0)
    const int lev = blockIdx.x & 7;              // 0..7 -> level 4+lev
    const int i = (blockIdx.x >> 3) * 256 + threadIdx.x;
    if (i >= npts) return;
    float scale = hs.s[0];
    #pragma unroll
    for (int k = 1; k < 8; ++k) if (lev == k) scale = hs.s[k];  // s_cselect x7
    const ushort_t* __restrict__ base =
        tabq + hash_off0 + ((unsigned)lev << 21);
    const unsigned m = (1u << 21) - 1u;

    int gp = pbase + i;
    float x0 = (pts[3 * gp + 0] + 1.f) * 0.5f;
    float x1 = (pts[3 * gp + 1] + 1.f) * 0.5f;
    float x2 = (pts[3 * gp + 2] + 1.f) * 0.5f;
    float p0 = x0 * scale + 0.5f;
    float p1 = x1 * scale + 0.5f;
    float p2 = x2 * scale + 0.5f;
    float f0 = floorf(p0), f1 = floorf(p1), f2 = floorf(p2);
    float r0 = p0 - f0, r1 = p1 - f1, r2 = p2 - f2;
    float u0 = 1.f - r0, u1 = 1.f - r1, u2 = 1.f - r2;
    unsigned g0 = (unsigned)f0, g1 = (unsigned)f1, g2 = (unsigned)f2;
    unsigned y0 = g1 * 2654435761u, y1 = y0 + 2654435761u;
    unsigned z0 = g2 * 805459861u,  z1 = z0 + 805459861u;
    int t[8];
    #pragma unroll
    for (int c = 0; c < 8; ++c) {
        unsigned h = (g0 + ((c & 1) ? 1u : 0u))
                   ^ ((c & 2) ? y1 : y0) ^ ((c & 4) ? z1 : z0);
        t[c] = (int)base[h & m];
    }
    float a0 = 0.f, a1 = 0.f;
    #pragma unroll
    for (int c = 0; c < 8; ++c) {
        float w = ((c & 1) ? r0 : u0) * ((c & 2) ? r1 : u1)
                * ((c & 4) ? r2 : u2);
        a0 = fmaf(w, __builtin_amdgcn_cvt_f32_fp8(t[c], 0), a0);
        a1 = fmaf(w, __builtin_amdgcn_cvt_f32_fp8(t[c], 1), a1);
    }
    __hip_bfloat162 o;
    o.x = __float2bfloat16(a0 * FP8_ISCALE);
    o.y = __float2bfloat16(a1 * FP8_ISCALE);
    feats[(size_t)(4 + lev) * npts + i] = o;
}

// ---------------------------------------------------------------------------
// MFMA per-line MLP + weighted |op-gt| sum. One block (4 waves) per line.
// A = feats (16 pts x K32, features 24..31 zero), B = W1 bf16 (K32 x 16),
// 4 n-blocks cover the 64 hidden units. b1 is preloaded into the accumulator.
// Layouts (gfx950 16x16x32 bf16):
//   A: lane l holds A[l&15][(l>>4)*8 + i]           (i = 0..7)
//   B: lane l holds B[(l>>4)*8 + i][l&15]
//   D: lane l holds D[(l>>4)*4 + r][l&15]           (r = 0..3)
__global__ void __launch_bounds__(256) mlp_loss_mfma_kernel(
        const unsigned* __restrict__ feats, int npts,
        const float* __restrict__ gt, int line0,
        const float* __restrict__ w1, const float* __restrict__ b1,
        const float* __restrict__ w2, const float* __restrict__ b2,
        float* __restrict__ S) {
    const int line_local = blockIdx.x;
    const int tid  = threadIdx.x;
    const int wave = tid >> 6;
    const int lane = tid & 63;
    const int c = lane & 15;      // hidden col within 16 / A point row
    const int g = lane >> 4;      // k-group (0..3)

    // Loop-invariant B fragments: W1[k][64] f32 -> bf16, K padded 24->32.
    short8_t bfrag[4];
    #pragma unroll
    for (int nb = 0; nb < 4; ++nb) {
        #pragma unroll
        for (int i = 0; i < 8; ++i) {
            int k = g * 8 + i;
            float v = (k < 24) ? w1[k * 64 + nb * 16 + c] : 0.f;
            bfrag[nb][i] = (short)f32_to_bf16_bits(v);
        }
    }
    float b1v[4], w2v[4];
    #pragma unroll
    for (int nb = 0; nb < 4; ++nb) {
        b1v[nb] = b1[nb * 16 + c];
        w2v[nb] = w2[nb * 16 + c];
    }
    const float b2v = b2[0];

    const size_t lbase = (size_t)line_local * P_PTS;
    float lsum = 0.f;

    // 16 iterations x 4 waves x 16 points = 1024 >= 1000 (tail masked).
    for (int it = 0; it < 16; ++it) {
        const int base16 = it * 64 + wave * 16;
        // --- A fragment: point row = c, k = g*8 + i (2 bf16 per level slab)
        int prow = base16 + c;
        int pcl  = prow < P_PTS ? prow : P_PTS - 1;
        size_t pidx = lbase + (size_t)pcl;
        union { unsigned u[4]; short8_t v; } a;
        if (g < 3) {
            #pragma unroll
            for (int s = 0; s < 4; ++s)
                a.u[s] = feats[(size_t)(g * 4 + s) * npts + pidx];
        } else {
            a.u[0] = 0u; a.u[1] = 0u; a.u[2] = 0u; a.u[3] = 0u;
        }
        // --- layer 1: 4 MFMAs, accumulator seeded with b1
        f32x4 acc[4];
        #pragma unroll
        for (int nb = 0; nb < 4; ++nb) {
            f32x4 ci = {b1v[nb], b1v[nb], b1v[nb], b1v[nb]};
            acc[nb] = __builtin_amdgcn_mfma_f32_16x16x32_bf16(
                a.v, bfrag[nb], ci, 0, 0, 0);
        }
        // --- layer 2: relu + dot with w2, reduce across the 16-lane group
        float part[4];
        #pragma unroll
        for (int r = 0; r < 4; ++r) {
            float s = fmaxf(acc[0][r], 0.f) * w2v[0];
            s = fmaf(fmaxf(acc[1][r], 0.f), w2v[1], s);
            s = fmaf(fmaxf(acc[2][r], 0.f), w2v[2], s);
            s = fmaf(fmaxf(acc[3][r], 0.f), w2v[3], s);
            part[r] = s;
        }
        #pragma unroll
        for (int off = 1; off < 16; off <<= 1) {
            #pragma unroll
            for (int r = 0; r < 4; ++r)
                part[r] += __shfl_xor(part[r], off);
        }
        // lane c<4 owns point p = base16 + g*4 + c (exactly one lane/point)
        if (c < 4) {
            int p = base16 + g * 4 + c;
            if (p < P_PTS) {
                float op = part[c] + b2v;
                float gv = gt[(size_t)(line0 + line_local) * P_PTS + p];
                float cw = (p < 500) ? (float)(4.0 / 3.0) : (float)(2.0 / 3.0);
                lsum += fabsf(op - gv) * cw;
            }
        }
    }
    float tot = block_reduce_256(lsum);
    if (tid == 0) S[line0 + line_local] = tot;
}

// ---------------------------------------------------------------------------
// Fallback monolithic opacity kernel (R1 structure) if ws is too small.
__global__ void __launch_bounds__(256) opacity_mono_kernel(
        const float* __restrict__ pts, const float* __restrict__ gt,
        const float2* __restrict__ tab,
        const float* __restrict__ w1, const float* __restrict__ b1,
        const float* __restrict__ w2, const float* __restrict__ b2,
        float* __restrict__ S, Specs sp) {
    const int b = blockIdx.x;
    const int tid = threadIdx.x;
    float lsum = 0.f;
    for (int p = tid; p < P_PTS; p += 256) {
        const int i = b * P_PTS + p;
        float x0 = (pts[3 * i + 0] + 1.f) * 0.5f;
        float x1 = (pts[3 * i + 1] + 1.f) * 0.5f;
        float x2 = (pts[3 * i + 2] + 1.f) * 0.5f;
        float feat[24];
        #pragma unroll
        for (int l = 0; l < NLEV; ++l) {
            const LevelSpec L = sp.L[l];
            float p0 = x0 * L.scale + 0.5f;
            float p1 = x1 * L.scale + 0.5f;
            float p2 = x2 * L.scale + 0.5f;
            float f0 = floorf(p0), f1 = floorf(p1), f2 = floorf(p2);
            float r0 = p0 - f0, r1 = p1 - f1, r2 = p2 - f2;
            float u0 = 1.f - r0, u1 = 1.f - r1, u2 = 1.f - r2;
            unsigned g0 = (unsigned)f0, g1 = (unsigned)f1, g2 = (unsigned)f2;
            float a0 = 0.f, a1 = 0.f;
            if (l >= 4) {
                unsigned y0 = g1 * 2654435761u, y1 = y0 + 2654435761u;
                unsigned z0 = g2 * 805459861u,  z1 = z0 + 805459861u;
                unsigned m = L.mask;
                #pragma unroll
                for (int c = 0; c < 8; ++c) {
                    unsigned h = (g0 + ((c & 1) ? 1u : 0u))
                               ^ ((c & 2) ? y1 : y0) ^ ((c & 4) ? z1 : z0);
                    float2 t = tab[L.off + (h & m)];
                    float w = ((c & 1) ? r0 : u0) * ((c & 2) ? r1 : u1)
                            * ((c & 4) ? r2 : u2);
                    a0 = fmaf(w, t.x, a0); a1 = fmaf(w, t.y, a1);
                }
            } else {
                unsigned R = L.R, R2 = R * R;
                unsigned y0 = g1 * R, y1 = y0 + R;
                unsigned z0 = g2 * R2, z1 = z0 + R2;
                #pragma unroll
                for (int c = 0; c < 8; ++c) {
                    unsigned idx = (g0 + ((c & 1) ? 1u : 0u))
                                 + ((c & 2) ? y1 : y0) + ((c & 4) ? z1 : z0);
                    float2 t = tab[L.off + idx];
                    float w = ((c & 1) ? r0 : u0) * ((c & 2) ? r1 : u1)
                            * ((c & 4) ? r2 : u2);
                    a0 = fmaf(w, t.x, a0); a1 = fmaf(w, t.y, a1);
                }
            }
            feat[2 * l] = a0; feat[2 * l + 1] = a1;
        }
        float op = mlp_24_64_1(feat, w1, b1, w2, b2);
        float cw = (p < 500) ? (float)(4.0 / 3.0) : (float)(2.0 / 3.0);
        lsum += fabsf(op - gt[i]) * cw;
    }
    float tot = block_reduce_256(lsum);
    if (tid == 0) S[b] = tot;
}

// Confidence (D=2, tiny) + final reduction: unchanged (f32 table).
__global__ void __launch_bounds__(256) conf_kernel(
        const float* __restrict__ line, const float2* __restrict__ tab,
        const float* __restrict__ w1, const float* __restrict__ b1,
        const float* __restrict__ w2, const float* __restrict__ b2,
        const float* __restrict__ S, float* __restrict__ partial, Specs sp) {
    const int b = blockIdx.x * 256 + threadIdx.x;
    float x0 = (line[2 * b + 0] + 1.f) * 0.5f;
    float x1 = (line[2 * b + 1] + 1.f) * 0.5f;
    float feat[24];
    #pragma unroll
    for (int l = 0; l < NLEV; ++l) {
        const unsigned off = sp.L[l].off;
        const float scale = sp.L[l].scale;
        float p0 = x0 * scale + 0.5f;
        float p1 = x1 * scale + 0.5f;
        float f0 = floorf(p0), f1 = floorf(p1);
        float r0 = p0 - f0, r1 = p1 - f1;
        float u0 = 1.f - r0, u1 = 1.f - r1;
        unsigned g0 = (unsigned)f0, g1 = (unsigned)f1;
        unsigned idx0, idx1, idx2, idx3;
        if (l >= 8) {
            const unsigned mask = sp.L[l].mask;
            unsigned a1 = g1 * 2654435761u, bb1 = a1 + 2654435761u;
            idx0 = (g0 ^ a1) & mask;
            idx1 = ((g0 + 1u) ^ a1) & mask;
            idx2 = (g0 ^ bb1) & mask;
            idx3 = ((g0 + 1u) ^ bb1) & mask;
        } else {
            const unsigned R = sp.L[l].R;
            unsigned a1 = g1 * R, bb1 = a1 + R;
            idx0 = g0 + a1; idx1 = g0 + 1u + a1;
            idx2 = g0 + bb1; idx3 = g0 + 1u + bb1;
        }
        float2 t0 = tab[off + idx0], t1 = tab[off + idx1];
        float2 t2 = tab[off + idx2], t3 = tab[off + idx3];
        float w0 = u0 * u1, w1c = r0 * u1, w2c = u0 * r1, w3 = r0 * r1;
        feat[2 * l]     = w0 * t0.x + w1c * t1.x + w2c * t2.x + w3 * t3.x;
        feat[2 * l + 1] = w0 * t0.y + w1c * t1.y + w2c * t2.y + w3 * t3.y;
    }
    float conf = mlp_24_64_1(feat, w1, b1, w2, b2);
    float term = expf(-conf) * (S[b] * (1.0f / (float)P_PTS)) + conf;
    float tot = block_reduce_256(term);
    if (threadIdx.x == 0) partial[blockIdx.x] = tot;
}

__global__ void final_kernel(const float* __restrict__ partial,
                             float* __restrict__ out) {
    if (threadIdx.x == 0) {
        float s = 0.f;
        for (int i = 0; i < 16; ++i) s += partial[i];
        out[0] = s * (1.0f / (float)B_LINES);
    }
}

// ---------------------------------------------------------------------------

extern "C" void kernel_launch(void* const* d_in, const int* in_sizes, int n_in,
                              void* d_out, int out_size, void* d_ws, size_t ws_size,
                              hipStream_t stream) {
    const float* line    = (const float*)d_in[0];
    const float* pts     = (const float*)d_in[1];
    const float* gt      = (const float*)d_in[2];
    const float* table_c = (const float*)d_in[3];
    const float* w1_c    = (const float*)d_in[4];
    const float* b1_c    = (const float*)d_in[5];
    const float* w2_c    = (const float*)d_in[6];
    const float* b2_c    = (const float*)d_in[7];
    const float* table_o = (const float*)d_in[8];
    const float* w1_o    = (const float*)d_in[9];
    const float* b1_o    = (const float*)d_in[10];
    const float* w2_o    = (const float*)d_in[11];
    const float* b2_o    = (const float*)d_in[12];
    (void)in_sizes; (void)n_in; (void)out_size;

    Specs sp3, sp2;
    unsigned tot3 = compute_specs(3, &sp3);
    compute_specs(2, &sp2);

    // ws layout: [fp8 table][S 4096][partial 16][feat slabs]
    size_t tabB = (((size_t)tot3 * 2) + 255) & ~(size_t)255;
    size_t head = tabB + (size_t)B_LINES * 4 + 64;
    head = (head + 63) & ~(size_t)63;
    long max_lines = 0;
    if (ws_size > head + 64)
        max_lines = (long)((ws_size - head - 64) / ((size_t)P_PTS * 12 * 4));

    float* S       = (float*)((char*)d_ws + tabB);
    float* partial = S + B_LINES;

    if (max_lines >= 64) {
        // Phased fp8 path.
        ushort_t* tabq = (ushort_t*)d_ws;
        __hip_bfloat162* featbuf = (__hip_bfloat162*)((char*)d_ws + head);

        // Single chunk when ws allows (round-0 counters: un-chunked featbuf
        // costs only ~17 us of HBM; chunking just multiplies launch count).
        int chunk_lines = (int)(max_lines < B_LINES ? max_lines : B_LINES);
        int nch = (B_LINES + chunk_lines - 1) / chunk_lines;

        HashScales hs;
        for (int k = 0; k < 8; ++k) hs.s[k] = sp3.L[4 + k].scale;
        const unsigned hash_off0 = sp3.L[4].off;

        convert_kernel<<<((int)tot3 + 255) / 256, 256, 0, stream>>>(
            (const float2*)table_o, tabq, (int)tot3);

        for (int ch = 0; ch < nch; ++ch) {
            int line0 = ch * chunk_lines;
            int lines = B_LINES - line0 < chunk_lines ? B_LINES - line0
                                                      : chunk_lines;
            int npts = lines * P_PTS;
            int pbase = line0 * P_PTS;
            int nblk = (npts + 255) / 256;
            enc_dense_kernel<<<nblk, 256, 0, stream>>>(
                pts, pbase, npts, tabq, featbuf, sp3);
            enc_hash_all_kernel<<<nblk * 8, 256, 0, stream>>>(
                pts, pbase, npts, tabq, hash_off0, hs, featbuf);
            mlp_loss_mfma_kernel<<<lines, 256, 0, stream>>>(
                (const unsigned*)featbuf, npts, gt, line0,
                w1_o, b1_o, w2_o, b2_o, S);
        }
    } else {
        // Fallback: monolithic f32 path (needs only S+partial in ws).
        opacity_mono_kernel<<<B_LINES, 256, 0, stream>>>(
            pts, gt, (const float2*)table_o, w1_o, b1_o, w2_o, b2_o, S, sp3);
    }

    conf_kernel<<<16, 256, 0, stream>>>(
        line, (const float2*)table_c, w1_c, b1_c, w2_c, b2_c, S, partial, sp2);
    final_kernel<<<1, 64, 0, stream>>>(partial, (float*)d_out);
}

// Round 3
// 1486.213 us; speedup vs baseline: 1.3265x; 1.0611x over previous
//
#include <hip/hip_runtime.h>
#include <hip/hip_bf16.h>
#include <math.h>

#define NLEV 12
#define B_LINES 4096
#define P_PTS 1000
#define FP8_SCALE 65536.0f
#define FP8_ISCALE (1.0f / 65536.0f)
#define NBLK_PER_LEV 256

typedef unsigned short ushort_t;
typedef __attribute__((ext_vector_type(8))) short short8_t;   // 8 bf16 (4 VGPRs)
typedef __attribute__((ext_vector_type(4))) float f32x4;

// Per-level table layout, mirrors _level_specs() exactly.
struct LevelSpec {
    unsigned off;    // entry offset into table (rows of 2 features)
    unsigned mask;   // params-1 (power-of-2 for hash levels)
    float    scale;  // BASE_RES * f^l - 1
    unsigned R;      // res + 1 (dense stride base)
};
struct Specs { LevelSpec L[NLEV]; };
struct HashScales { float s[8]; };   // scales for levels 4..11

static unsigned compute_specs(int D, Specs* sp) {
    double f = pow(8192.0 / 16.0, 1.0 / 11.0);
    unsigned offset = 0;
    for (int l = 0; l < NLEV; ++l) {
        double scale = 16.0 * pow(f, (double)l) - 1.0;
        int res = (int)ceil(scale) + 1;
        unsigned long long dense = 1ull;
        for (int d = 0; d < D; ++d) dense *= (unsigned long long)(res + 1);
        unsigned long long params = dense > (1ull << 21) ? (1ull << 21) : dense;
        params = ((params + 7ull) / 8ull) * 8ull;
        sp->L[l].off   = offset;
        sp->L[l].mask  = (unsigned)params - 1u;
        sp->L[l].scale = (float)scale;
        sp->L[l].R     = (unsigned)(res + 1);
        offset += (unsigned)params;
    }
    return offset;  // total entries
}

// ---------------------------------------------------------------------------

__device__ __forceinline__ float block_reduce_256(float v) {
    __shared__ float red[256];
    int tid = threadIdx.x;
    red[tid] = v;
    __syncthreads();
    #pragma unroll
    for (int s = 128; s >= 1; s >>= 1) {
        if (tid < s) red[tid] += red[tid + s];
        __syncthreads();
    }
    return red[0];
}

__device__ __forceinline__ unsigned short f32_to_bf16_bits(float f) {
    unsigned u = __float_as_uint(f);
    unsigned r = (u + 0x7fffu + ((u >> 16) & 1u)) >> 16;   // RNE
    return (unsigned short)r;
}

// bf16x2 pack + non-temporal store (evict-first: don't displace table lines).
__device__ __forceinline__ void store_nt_feat(__hip_bfloat162* p,
                                              float a0, float a1) {
    union { __hip_bfloat162 b; unsigned u; } cv;
    cv.b.x = __float2bfloat16(a0 * FP8_ISCALE);
    cv.b.y = __float2bfloat16(a1 * FP8_ISCALE);
    __builtin_nontemporal_store(cv.u, (unsigned*)p);
}

// MLP 24 -> 64(relu) -> 1; weights wave-uniform -> s_load + v_fmac.
// (used by the fallback mono path and conf path)
__device__ __forceinline__ float mlp_24_64_1(const float feat[24],
        const float* __restrict__ w1, const float* __restrict__ b1,
        const float* __restrict__ w2, const float* __restrict__ b2) {
    float o = b2[0];
    #pragma unroll
    for (int half = 0; half < 2; ++half) {
        float h[32];
        #pragma unroll
        for (int j = 0; j < 32; ++j) h[j] = b1[half * 32 + j];
        #pragma unroll
        for (int k = 0; k < 24; ++k) {
            float fv = feat[k];
            #pragma unroll
            for (int j = 0; j < 32; ++j)
                h[j] = fmaf(fv, w1[k * 64 + half * 32 + j], h[j]);
        }
        #pragma unroll
        for (int j = 0; j < 32; ++j)
            o = fmaf(fmaxf(h[j], 0.f), w2[half * 32 + j], o);
    }
    return o;
}

// ---------------------------------------------------------------------------
// fp8 table conversion: one row (2 features) -> 2 bytes, scaled by 2^16.
__global__ void __launch_bounds__(256) convert_kernel(
        const float2* __restrict__ in, ushort_t* __restrict__ out, int n) {
    int i = blockIdx.x * 256 + threadIdx.x;
    if (i >= n) return;
    float2 v;
    v.x = __builtin_nontemporal_load(&in[i].x);
    v.y = __builtin_nontemporal_load(&in[i].y);
    int p = __builtin_amdgcn_cvt_pk_fp8_f32(v.x * FP8_SCALE, v.y * FP8_SCALE,
                                            0, false);
    __builtin_nontemporal_store((ushort_t)(p & 0xffff), &out[i]);
}

// Dense levels 0..3 (combined fp8 footprint ~1.8 MB: L2-resident).
__global__ void __launch_bounds__(256) enc_dense_kernel(
        const float* __restrict__ pts, int pbase, int npts,
        const ushort_t* __restrict__ tabq,
        __hip_bfloat162* __restrict__ feats,   // 12 slabs of npts
        Specs sp) {
    int i = blockIdx.x * 256 + threadIdx.x;
    if (i >= npts) return;
    int gp = pbase + i;
    float x0 = (__builtin_nontemporal_load(pts + 3 * gp + 0) + 1.f) * 0.5f;
    float x1 = (__builtin_nontemporal_load(pts + 3 * gp + 1) + 1.f) * 0.5f;
    float x2 = (__builtin_nontemporal_load(pts + 3 * gp + 2) + 1.f) * 0.5f;
    #pragma unroll
    for (int l = 0; l < 4; ++l) {
        const LevelSpec L = sp.L[l];
        float p0 = x0 * L.scale + 0.5f;
        float p1 = x1 * L.scale + 0.5f;
        float p2 = x2 * L.scale + 0.5f;
        float f0 = floorf(p0), f1 = floorf(p1), f2 = floorf(p2);
        float r0 = p0 - f0, r1 = p1 - f1, r2 = p2 - f2;
        float u0 = 1.f - r0, u1 = 1.f - r1, u2 = 1.f - r2;
        unsigned g0 = (unsigned)f0, g1 = (unsigned)f1, g2 = (unsigned)f2;
        const ushort_t* __restrict__ base = tabq + L.off;
        unsigned R = L.R, R2 = R * R;
        unsigned y0 = g1 * R, y1 = y0 + R;
        unsigned z0 = g2 * R2, z1 = z0 + R2;
        int t[8];
        #pragma unroll
        for (int c = 0; c < 8; ++c) {
            unsigned idx = (g0 + ((c & 1) ? 1u : 0u))
                         + ((c & 2) ? y1 : y0) + ((c & 4) ? z1 : z0);
            t[c] = (int)base[idx];
        }
        float a0 = 0.f, a1 = 0.f;
        #pragma unroll
        for (int c = 0; c < 8; ++c) {
            float w = ((c & 1) ? r0 : u0) * ((c & 2) ? r1 : u1)
                    * ((c & 4) ? r2 : u2);
            a0 = fmaf(w, __builtin_amdgcn_cvt_f32_fp8(t[c], 0), a0);
            a1 = fmaf(w, __builtin_amdgcn_cvt_f32_fp8(t[c], 1), a1);
        }
        store_nt_feat(&feats[(size_t)l * npts + i], a0, a1);
    }
}

// Per-point hash addresses + fractional weights.
struct HashPt { unsigned h[8]; float r0, r1, r2; };

__device__ __forceinline__ HashPt hash_addrs(
        const float* __restrict__ pts, int gp, float scale, unsigned m) {
    float x0 = (__builtin_nontemporal_load(pts + 3 * gp + 0) + 1.f) * 0.5f;
    float x1 = (__builtin_nontemporal_load(pts + 3 * gp + 1) + 1.f) * 0.5f;
    float x2 = (__builtin_nontemporal_load(pts + 3 * gp + 2) + 1.f) * 0.5f;
    float p0 = x0 * scale + 0.5f;
    float p1 = x1 * scale + 0.5f;
    float p2 = x2 * scale + 0.5f;
    float f0 = floorf(p0), f1 = floorf(p1), f2 = floorf(p2);
    HashPt o;
    o.r0 = p0 - f0; o.r1 = p1 - f1; o.r2 = p2 - f2;
    unsigned g0 = (unsigned)f0, g1 = (unsigned)f1, g2 = (unsigned)f2;
    unsigned y0 = g1 * 2654435761u, y1 = y0 + 2654435761u;
    unsigned z0 = g2 * 805459861u,  z1 = z0 + 805459861u;
    #pragma unroll
    for (int c = 0; c < 8; ++c) {
        unsigned h = (g0 + ((c & 1) ? 1u : 0u))
                   ^ ((c & 2) ? y1 : y0) ^ ((c & 4) ? z1 : z0);
        o.h[c] = h & m;
    }
    return o;
}

__device__ __forceinline__ void interp_store(
        const int t[8], const HashPt& hp, __hip_bfloat162* dst) {
    float u0 = 1.f - hp.r0, u1 = 1.f - hp.r1, u2 = 1.f - hp.r2;
    float a0 = 0.f, a1 = 0.f;
    #pragma unroll
    for (int c = 0; c < 8; ++c) {
        float w = ((c & 1) ? hp.r0 : u0) * ((c & 2) ? hp.r1 : u1)
                * ((c & 4) ? hp.r2 : u2);
        a0 = fmaf(w, __builtin_amdgcn_cvt_f32_fp8(t[c], 0), a0);
        a1 = fmaf(w, __builtin_amdgcn_cvt_f32_fp8(t[c], 1), a1);
    }
    store_nt_feat(dst, a0, a1);
}

// All 8 hash levels in ONE persistent launch, XCD-pinned: level = blockIdx&7,
// so with round-robin block->XCD dispatch each XCD's 4 MB L2 holds exactly
// ONE level's 4 MB fp8 table for the whole kernel. Persistent grid (2048
// blocks) + 2 pts/thread: ~16 gathers in flight/thread, full occupancy.
__global__ void __launch_bounds__(256) enc_hash_all_kernel(
        const float* __restrict__ pts, int pbase, int npts,
        const ushort_t* __restrict__ tabq, unsigned hash_off0,
        HashScales hs,
        __hip_bfloat162* __restrict__ feats) {   // slab base (level 0)
    const int lev = blockIdx.x & 7;              // 0..7 -> level 4+lev
    const int bpl = blockIdx.x >> 3;             // block index within level
    const int tid = threadIdx.x;
    float scale = hs.s[0];
    #pragma unroll
    for (int k = 1; k < 8; ++k) if (lev == k) scale = hs.s[k];  // cselect x7
    const ushort_t* __restrict__ base =
        tabq + hash_off0 + ((unsigned)lev << 21);
    const unsigned m = (1u << 21) - 1u;
    __hip_bfloat162* __restrict__ slab = feats + (size_t)(4 + lev) * npts;

    const int stride = NBLK_PER_LEV * 512;
    for (int p0 = bpl * 512; p0 < npts; p0 += stride) {
        int iA = p0 + tid;
        int iB = iA + 256;
        bool vA = iA < npts, vB = iB < npts;
        int icA = vA ? iA : npts - 1;
        int icB = vB ? iB : npts - 1;
        HashPt hA = hash_addrs(pts, pbase + icA, scale, m);
        HashPt hB = hash_addrs(pts, pbase + icB, scale, m);
        int tA[8], tB[8];
        #pragma unroll
        for (int c = 0; c < 8; ++c) tA[c] = (int)base[hA.h[c]];
        #pragma unroll
        for (int c = 0; c < 8; ++c) tB[c] = (int)base[hB.h[c]];
        if (vA) interp_store(tA, hA, slab + iA);
        if (vB) interp_store(tB, hB, slab + iB);
    }
}

// ---------------------------------------------------------------------------
// MFMA per-line MLP + weighted |op-gt| sum. One block (4 waves) per line.
// A = feats (16 pts x K32, features 24..31 zero), B = W1 bf16 (K32 x 16),
// 4 n-blocks cover the 64 hidden units. b1 is preloaded into the accumulator.
// Layouts (gfx950 16x16x32 bf16):
//   A: lane l holds A[l&15][(l>>4)*8 + i]           (i = 0..7)
//   B: lane l holds B[(l>>4)*8 + i][l&15]
//   D: lane l holds D[(l>>4)*4 + r][l&15]           (r = 0..3)
__global__ void __launch_bounds__(256) mlp_loss_mfma_kernel(
        const unsigned* __restrict__ feats, int npts,
        const float* __restrict__ gt, int line0,
        const float* __restrict__ w1, const float* __restrict__ b1,
        const float* __restrict__ w2, const float* __restrict__ b2,
        float* __restrict__ S) {
    const int line_local = blockIdx.x;
    const int tid  = threadIdx.x;
    const int wave = tid >> 6;
    const int lane = tid & 63;
    const int c = lane & 15;      // hidden col within 16 / A point row
    const int g = lane >> 4;      // k-group (0..3)

    // Loop-invariant B fragments: W1[k][64] f32 -> bf16, K padded 24->32.
    short8_t bfrag[4];
    #pragma unroll
    for (int nb = 0; nb < 4; ++nb) {
        #pragma unroll
        for (int i = 0; i < 8; ++i) {
            int k = g * 8 + i;
            float v = (k < 24) ? w1[k * 64 + nb * 16 + c] : 0.f;
            bfrag[nb][i] = (short)f32_to_bf16_bits(v);
        }
    }
    float b1v[4], w2v[4];
    #pragma unroll
    for (int nb = 0; nb < 4; ++nb) {
        b1v[nb] = b1[nb * 16 + c];
        w2v[nb] = w2[nb * 16 + c];
    }
    const float b2v = b2[0];

    const size_t lbase = (size_t)line_local * P_PTS;
    float lsum = 0.f;

    // 16 iterations x 4 waves x 16 points = 1024 >= 1000 (tail masked).
    for (int it = 0; it < 16; ++it) {
        const int base16 = it * 64 + wave * 16;
        // --- A fragment: point row = c, k = g*8 + i (2 bf16 per level slab)
        int prow = base16 + c;
        int pcl  = prow < P_PTS ? prow : P_PTS - 1;
        size_t pidx = lbase + (size_t)pcl;
        union { unsigned u[4]; short8_t v; } a;
        if (g < 3) {
            #pragma unroll
            for (int s = 0; s < 4; ++s)
                a.u[s] = feats[(size_t)(g * 4 + s) * npts + pidx];
        } else {
            a.u[0] = 0u; a.u[1] = 0u; a.u[2] = 0u; a.u[3] = 0u;
        }
        // --- layer 1: 4 MFMAs, accumulator seeded with b1
        f32x4 acc[4];
        #pragma unroll
        for (int nb = 0; nb < 4; ++nb) {
            f32x4 ci = {b1v[nb], b1v[nb], b1v[nb], b1v[nb]};
            acc[nb] = __builtin_amdgcn_mfma_f32_16x16x32_bf16(
                a.v, bfrag[nb], ci, 0, 0, 0);
        }
        // --- layer 2: relu + dot with w2, reduce across the 16-lane group
        float part[4];
        #pragma unroll
        for (int r = 0; r < 4; ++r) {
            float s = fmaxf(acc[0][r], 0.f) * w2v[0];
            s = fmaf(fmaxf(acc[1][r], 0.f), w2v[1], s);
            s = fmaf(fmaxf(acc[2][r], 0.f), w2v[2], s);
            s = fmaf(fmaxf(acc[3][r], 0.f), w2v[3], s);
            part[r] = s;
        }
        #pragma unroll
        for (int off = 1; off < 16; off <<= 1) {
            #pragma unroll
            for (int r = 0; r < 4; ++r)
                part[r] += __shfl_xor(part[r], off);
        }
        // lane c<4 owns point p = base16 + g*4 + c (exactly one lane/point)
        if (c < 4) {
            int p = base16 + g * 4 + c;
            if (p < P_PTS) {
                float op = part[c] + b2v;
                float gv = gt[(size_t)(line0 + line_local) * P_PTS + p];
                float cw = (p < 500) ? (float)(4.0 / 3.0) : (float)(2.0 / 3.0);
                lsum += fabsf(op - gv) * cw;
            }
        }
    }
    float tot = block_reduce_256(lsum);
    if (tid == 0) S[line0 + line_local] = tot;
}

// ---------------------------------------------------------------------------
// Fallback monolithic opacity kernel (R1 structure) if ws is too small.
__global__ void __launch_bounds__(256) opacity_mono_kernel(
        const float* __restrict__ pts, const float* __restrict__ gt,
        const float2* __restrict__ tab,
        const float* __restrict__ w1, const float* __restrict__ b1,
        const float* __restrict__ w2, const float* __restrict__ b2,
        float* __restrict__ S, Specs sp) {
    const int b = blockIdx.x;
    const int tid = threadIdx.x;
    float lsum = 0.f;
    for (int p = tid; p < P_PTS; p += 256) {
        const int i = b * P_PTS + p;
        float x0 = (pts[3 * i + 0] + 1.f) * 0.5f;
        float x1 = (pts[3 * i + 1] + 1.f) * 0.5f;
        float x2 = (pts[3 * i + 2] + 1.f) * 0.5f;
        float feat[24];
        #pragma unroll
        for (int l = 0; l < NLEV; ++l) {
            const LevelSpec L = sp.L[l];
            float p0 = x0 * L.scale + 0.5f;
            float p1 = x1 * L.scale + 0.5f;
            float p2 = x2 * L.scale + 0.5f;
            float f0 = floorf(p0), f1 = floorf(p1), f2 = floorf(p2);
            float r0 = p0 - f0, r1 = p1 - f1, r2 = p2 - f2;
            float u0 = 1.f - r0, u1 = 1.f - r1, u2 = 1.f - r2;
            unsigned g0 = (unsigned)f0, g1 = (unsigned)f1, g2 = (unsigned)f2;
            float a0 = 0.f, a1 = 0.f;
            if (l >= 4) {
                unsigned y0 = g1 * 2654435761u, y1 = y0 + 2654435761u;
                unsigned z0 = g2 * 805459861u,  z1 = z0 + 805459861u;
                unsigned m = L.mask;
                #pragma unroll
                for (int c = 0; c < 8; ++c) {
                    unsigned h = (g0 + ((c & 1) ? 1u : 0u))
                               ^ ((c & 2) ? y1 : y0) ^ ((c & 4) ? z1 : z0);
                    float2 t = tab[L.off + (h & m)];
                    float w = ((c & 1) ? r0 : u0) * ((c & 2) ? r1 : u1)
                            * ((c & 4) ? r2 : u2);
                    a0 = fmaf(w, t.x, a0); a1 = fmaf(w, t.y, a1);
                }
            } else {
                unsigned R = L.R, R2 = R * R;
                unsigned y0 = g1 * R, y1 = y0 + R;
                unsigned z0 = g2 * R2, z1 = z0 + R2;
                #pragma unroll
                for (int c = 0; c < 8; ++c) {
                    unsigned idx = (g0 + ((c & 1) ? 1u : 0u))
                                 + ((c & 2) ? y1 : y0) + ((c & 4) ? z1 : z0);
                    float2 t = tab[L.off + idx];
                    float w = ((c & 1) ? r0 : u0) * ((c & 2) ? r1 : u1)
                            * ((c & 4) ? r2 : u2);
                    a0 = fmaf(w, t.x, a0); a1 = fmaf(w, t.y, a1);
                }
            }
            feat[2 * l] = a0; feat[2 * l + 1] = a1;
        }
        float op = mlp_24_64_1(feat, w1, b1, w2, b2);
        float cw = (p < 500) ? (float)(4.0 / 3.0) : (float)(2.0 / 3.0);
        lsum += fabsf(op - gt[i]) * cw;
    }
    float tot = block_reduce_256(lsum);
    if (tid == 0) S[b] = tot;
}

// Confidence (D=2, tiny) + final reduction: unchanged (f32 table).
__global__ void __launch_bounds__(256) conf_kernel(
        const float* __restrict__ line, const float2* __restrict__ tab,
        const float* __restrict__ w1, const float* __restrict__ b1,
        const float* __restrict__ w2, const float* __restrict__ b2,
        const float* __restrict__ S, float* __restrict__ partial, Specs sp) {
    const int b = blockIdx.x * 256 + threadIdx.x;
    float x0 = (line[2 * b + 0] + 1.f) * 0.5f;
    float x1 = (line[2 * b + 1] + 1.f) * 0.5f;
    float feat[24];
    #pragma unroll
    for (int l = 0; l < NLEV; ++l) {
        const unsigned off = sp.L[l].off;
        const float scale = sp.L[l].scale;
        float p0 = x0 * scale + 0.5f;
        float p1 = x1 * scale + 0.5f;
        float f0 = floorf(p0), f1 = floorf(p1);
        float r0 = p0 - f0, r1 = p1 - f1;
        float u0 = 1.f - r0, u1 = 1.f - r1;
        unsigned g0 = (unsigned)f0, g1 = (unsigned)f1;
        unsigned idx0, idx1, idx2, idx3;
        if (l >= 8) {
            const unsigned mask = sp.L[l].mask;
            unsigned a1 = g1 * 2654435761u, bb1 = a1 + 2654435761u;
            idx0 = (g0 ^ a1) & mask;
            idx1 = ((g0 + 1u) ^ a1) & mask;
            idx2 = (g0 ^ bb1) & mask;
            idx3 = ((g0 + 1u) ^ bb1) & mask;
        } else {
            const unsigned R = sp.L[l].R;
            unsigned a1 = g1 * R, bb1 = a1 + R;
            idx0 = g0 + a1; idx1 = g0 + 1u + a1;
            idx2 = g0 + bb1; idx3 = g0 + 1u + bb1;
        }
        float2 t0 = tab[off + idx0], t1 = tab[off + idx1];
        float2 t2 = tab[off + idx2], t3 = tab[off + idx3];
        float w0 = u0 * u1, w1c = r0 * u1, w2c = u0 * r1, w3 = r0 * r1;
        feat[2 * l]     = w0 * t0.x + w1c * t1.x + w2c * t2.x + w3 * t3.x;
        feat[2 * l + 1] = w0 * t0.y + w1c * t1.y + w2c * t2.y + w3 * t3.y;
    }
    float conf = mlp_24_64_1(feat, w1, b1, w2, b2);
    float term = expf(-conf) * (S[b] * (1.0f / (float)P_PTS)) + conf;
    float tot = block_reduce_256(term);
    if (threadIdx.x == 0) partial[blockIdx.x] = tot;
}

__global__ void final_kernel(const float* __restrict__ partial,
                             float* __restrict__ out) {
    if (threadIdx.x == 0) {
        float s = 0.f;
        for (int i = 0; i < 16; ++i) s += partial[i];
        out[0] = s * (1.0f / (float)B_LINES);
    }
}

// ---------------------------------------------------------------------------

extern "C" void kernel_launch(void* const* d_in, const int* in_sizes, int n_in,
                              void* d_out, int out_size, void* d_ws, size_t ws_size,
                              hipStream_t stream) {
    const float* line    = (const float*)d_in[0];
    const float* pts     = (const float*)d_in[1];
    const float* gt      = (const float*)d_in[2];
    const float* table_c = (const float*)d_in[3];
    const float* w1_c    = (const float*)d_in[4];
    const float* b1_c    = (const float*)d_in[5];
    const float* w2_c    = (const float*)d_in[6];
    const float* b2_c    = (const float*)d_in[7];
    const float* table_o = (const float*)d_in[8];
    const float* w1_o    = (const float*)d_in[9];
    const float* b1_o    = (const float*)d_in[10];
    const float* w2_o    = (const float*)d_in[11];
    const float* b2_o    = (const float*)d_in[12];
    (void)in_sizes; (void)n_in; (void)out_size;

    Specs sp3, sp2;
    unsigned tot3 = compute_specs(3, &sp3);
    compute_specs(2, &sp2);

    // ws layout: [fp8 table][S 4096][partial 16][feat slabs]
    size_t tabB = (((size_t)tot3 * 2) + 255) & ~(size_t)255;
    size_t head = tabB + (size_t)B_LINES * 4 + 64;
    head = (head + 63) & ~(size_t)63;
    long max_lines = 0;
    if (ws_size > head + 64)
        max_lines = (long)((ws_size - head - 64) / ((size_t)P_PTS * 12 * 4));

    float* S       = (float*)((char*)d_ws + tabB);
    float* partial = S + B_LINES;

    if (max_lines >= 64) {
        // Phased fp8 path.
        ushort_t* tabq = (ushort_t*)d_ws;
        __hip_bfloat162* featbuf = (__hip_bfloat162*)((char*)d_ws + head);

        int chunk_lines = (int)(max_lines < B_LINES ? max_lines : B_LINES);
        int nch = (B_LINES + chunk_lines - 1) / chunk_lines;

        HashScales hs;
        for (int k = 0; k < 8; ++k) hs.s[k] = sp3.L[4 + k].scale;
        const unsigned hash_off0 = sp3.L[4].off;

        convert_kernel<<<((int)tot3 + 255) / 256, 256, 0, stream>>>(
            (const float2*)table_o, tabq, (int)tot3);

        for (int ch = 0; ch < nch; ++ch) {
            int line0 = ch * chunk_lines;
            int lines = B_LINES - line0 < chunk_lines ? B_LINES - line0
                                                      : chunk_lines;
            int npts = lines * P_PTS;
            int pbase = line0 * P_PTS;
            int nblk = (npts + 255) / 256;
            enc_dense_kernel<<<nblk, 256, 0, stream>>>(
                pts, pbase, npts, tabq, featbuf, sp3);
            enc_hash_all_kernel<<<NBLK_PER_LEV * 8, 256, 0, stream>>>(
                pts, pbase, npts, tabq, hash_off0, hs, featbuf);
            mlp_loss_mfma_kernel<<<lines, 256, 0, stream>>>(
                (const unsigned*)featbuf, npts, gt, line0,
                w1_o, b1_o, w2_o, b2_o, S);
        }
    } else {
        // Fallback: monolithic f32 path (needs only S+partial in ws).
        opacity_mono_kernel<<<B_LINES, 256, 0, stream>>>(
            pts, gt, (const float2*)table_o, w1_o, b1_o, w2_o, b2_o, S, sp3);
    }

    conf_kernel<<<16, 256, 0, stream>>>(
        line, (const float2*)table_c, w1_c, b1_c, w2_c, b2_c, S, partial, sp2);
    final_kernel<<<1, 64, 0, stream>>>(partial, (float*)d_out);
}

// Round 4
// 1410.120 us; speedup vs baseline: 1.3981x; 1.0540x over previous
//
#include <hip/hip_runtime.h>
#include <hip/hip_bf16.h>
#include <math.h>

#define NLEV 12
#define B_LINES 4096
#define P_PTS 1000
#define FP8_SCALE 65536.0f
#define FP8_ISCALE (1.0f / 65536.0f)
#define NBLK_PER_LEV 256

typedef unsigned short ushort_t;
typedef __attribute__((ext_vector_type(8))) short short8_t;   // 8 bf16 (4 VGPRs)
typedef __attribute__((ext_vector_type(4))) float f32x4;

// Per-level table layout, mirrors _level_specs() exactly.
struct LevelSpec {
    unsigned off;    // entry offset into table (rows of 2 features)
    unsigned mask;   // params-1 (power-of-2 for hash levels)
    float    scale;  // BASE_RES * f^l - 1
    unsigned R;      // res + 1 (dense stride base)
};
struct Specs { LevelSpec L[NLEV]; };
struct HashScales { float s[8]; };   // scales for levels 4..11

static unsigned compute_specs(int D, Specs* sp) {
    double f = pow(8192.0 / 16.0, 1.0 / 11.0);
    unsigned offset = 0;
    for (int l = 0; l < NLEV; ++l) {
        double scale = 16.0 * pow(f, (double)l) - 1.0;
        int res = (int)ceil(scale) + 1;
        unsigned long long dense = 1ull;
        for (int d = 0; d < D; ++d) dense *= (unsigned long long)(res + 1);
        unsigned long long params = dense > (1ull << 21) ? (1ull << 21) : dense;
        params = ((params + 7ull) / 8ull) * 8ull;
        sp->L[l].off   = offset;
        sp->L[l].mask  = (unsigned)params - 1u;
        sp->L[l].scale = (float)scale;
        sp->L[l].R     = (unsigned)(res + 1);
        offset += (unsigned)params;
    }
    return offset;  // total entries
}

// ---------------------------------------------------------------------------

__device__ __forceinline__ float block_reduce_256(float v) {
    __shared__ float red[256];
    int tid = threadIdx.x;
    red[tid] = v;
    __syncthreads();
    #pragma unroll
    for (int s = 128; s >= 1; s >>= 1) {
        if (tid < s) red[tid] += red[tid + s];
        __syncthreads();
    }
    return red[0];
}

__device__ __forceinline__ unsigned short f32_to_bf16_bits(float f) {
    unsigned u = __float_as_uint(f);
    unsigned r = (u + 0x7fffu + ((u >> 16) & 1u)) >> 16;   // RNE
    return (unsigned short)r;
}

// bf16x2 pack + non-temporal store (evict-first: don't displace table lines).
__device__ __forceinline__ void store_nt_feat(__hip_bfloat162* p,
                                              float a0, float a1) {
    union { __hip_bfloat162 b; unsigned u; } cv;
    cv.b.x = __float2bfloat16(a0 * FP8_ISCALE);
    cv.b.y = __float2bfloat16(a1 * FP8_ISCALE);
    __builtin_nontemporal_store(cv.u, (unsigned*)p);
}

// MLP 24 -> 64(relu) -> 1; weights wave-uniform -> s_load + v_fmac.
// (used by the fallback mono path and conf path)
__device__ __forceinline__ float mlp_24_64_1(const float feat[24],
        const float* __restrict__ w1, const float* __restrict__ b1,
        const float* __restrict__ w2, const float* __restrict__ b2) {
    float o = b2[0];
    #pragma unroll
    for (int half = 0; half < 2; ++half) {
        float h[32];
        #pragma unroll
        for (int j = 0; j < 32; ++j) h[j] = b1[half * 32 + j];
        #pragma unroll
        for (int k = 0; k < 24; ++k) {
            float fv = feat[k];
            #pragma unroll
            for (int j = 0; j < 32; ++j)
                h[j] = fmaf(fv, w1[k * 64 + half * 32 + j], h[j]);
        }
        #pragma unroll
        for (int j = 0; j < 32; ++j)
            o = fmaf(fmaxf(h[j], 0.f), w2[half * 32 + j], o);
    }
    return o;
}

// ---------------------------------------------------------------------------
// fp8 table conversion: one row (2 features) -> 2 bytes, scaled by 2^16.
__global__ void __launch_bounds__(256) convert_kernel(
        const float2* __restrict__ in, ushort_t* __restrict__ out, int n) {
    int i = blockIdx.x * 256 + threadIdx.x;
    if (i >= n) return;
    float2 v;
    v.x = __builtin_nontemporal_load(&in[i].x);
    v.y = __builtin_nontemporal_load(&in[i].y);
    int p = __builtin_amdgcn_cvt_pk_fp8_f32(v.x * FP8_SCALE, v.y * FP8_SCALE,
                                            0, false);
    __builtin_nontemporal_store((ushort_t)(p & 0xffff), &out[i]);
}

// Dense levels 0..3 (combined fp8 footprint ~1.8 MB: L2-resident).
// Plain (cached) pts loads: this kernel runs first and warms L3 with the
// 49 MB pts stream for the hash kernel that follows.
__global__ void __launch_bounds__(256) enc_dense_kernel(
        const float* __restrict__ pts, int pbase, int npts,
        const ushort_t* __restrict__ tabq,
        __hip_bfloat162* __restrict__ feats,   // 12 slabs of npts
        Specs sp) {
    int i = blockIdx.x * 256 + threadIdx.x;
    if (i >= npts) return;
    int gp = pbase + i;
    float x0 = (pts[3 * gp + 0] + 1.f) * 0.5f;
    float x1 = (pts[3 * gp + 1] + 1.f) * 0.5f;
    float x2 = (pts[3 * gp + 2] + 1.f) * 0.5f;
    #pragma unroll
    for (int l = 0; l < 4; ++l) {
        const LevelSpec L = sp.L[l];
        float p0 = x0 * L.scale + 0.5f;
        float p1 = x1 * L.scale + 0.5f;
        float p2 = x2 * L.scale + 0.5f;
        float f0 = floorf(p0), f1 = floorf(p1), f2 = floorf(p2);
        float r0 = p0 - f0, r1 = p1 - f1, r2 = p2 - f2;
        float u0 = 1.f - r0, u1 = 1.f - r1, u2 = 1.f - r2;
        unsigned g0 = (unsigned)f0, g1 = (unsigned)f1, g2 = (unsigned)f2;
        const ushort_t* __restrict__ base = tabq + L.off;
        unsigned R = L.R, R2 = R * R;
        unsigned y0 = g1 * R, y1 = y0 + R;
        unsigned z0 = g2 * R2, z1 = z0 + R2;
        int t[8];
        #pragma unroll
        for (int c = 0; c < 8; ++c) {
            unsigned idx = (g0 + ((c & 1) ? 1u : 0u))
                         + ((c & 2) ? y1 : y0) + ((c & 4) ? z1 : z0);
            t[c] = (int)base[idx];
        }
        float a0 = 0.f, a1 = 0.f;
        #pragma unroll
        for (int c = 0; c < 8; ++c) {
            float w = ((c & 1) ? r0 : u0) * ((c & 2) ? r1 : u1)
                    * ((c & 4) ? r2 : u2);
            a0 = fmaf(w, __builtin_amdgcn_cvt_f32_fp8(t[c], 0), a0);
            a1 = fmaf(w, __builtin_amdgcn_cvt_f32_fp8(t[c], 1), a1);
        }
        store_nt_feat(&feats[(size_t)l * npts + i], a0, a1);
    }
}

// Per-point hash addresses + fractional weights (plain cached pts loads:
// pts sit in L3 after the dense pass; nt loads here caused HBM refetch
// of 49 MB x 8 levels in R3 — measured FETCH 404 MB).
struct HashPt { unsigned h[8]; float r0, r1, r2; };

__device__ __forceinline__ HashPt hash_addrs(
        const float* __restrict__ pts, int gp, float scale, unsigned m) {
    float x0 = (pts[3 * gp + 0] + 1.f) * 0.5f;
    float x1 = (pts[3 * gp + 1] + 1.f) * 0.5f;
    float x2 = (pts[3 * gp + 2] + 1.f) * 0.5f;
    float p0 = x0 * scale + 0.5f;
    float p1 = x1 * scale + 0.5f;
    float p2 = x2 * scale + 0.5f;
    float f0 = floorf(p0), f1 = floorf(p1), f2 = floorf(p2);
    HashPt o;
    o.r0 = p0 - f0; o.r1 = p1 - f1; o.r2 = p2 - f2;
    unsigned g0 = (unsigned)f0, g1 = (unsigned)f1, g2 = (unsigned)f2;
    unsigned y0 = g1 * 2654435761u, y1 = y0 + 2654435761u;
    unsigned z0 = g2 * 805459861u,  z1 = z0 + 805459861u;
    #pragma unroll
    for (int c = 0; c < 8; ++c) {
        unsigned h = (g0 + ((c & 1) ? 1u : 0u))
                   ^ ((c & 2) ? y1 : y0) ^ ((c & 4) ? z1 : z0);
        o.h[c] = h & m;
    }
    return o;
}

__device__ __forceinline__ void interp_store(
        const int t[8], const HashPt& hp, __hip_bfloat162* dst) {
    float u0 = 1.f - hp.r0, u1 = 1.f - hp.r1, u2 = 1.f - hp.r2;
    float a0 = 0.f, a1 = 0.f;
    #pragma unroll
    for (int c = 0; c < 8; ++c) {
        float w = ((c & 1) ? hp.r0 : u0) * ((c & 2) ? hp.r1 : u1)
                * ((c & 4) ? hp.r2 : u2);
        a0 = fmaf(w, __builtin_amdgcn_cvt_f32_fp8(t[c], 0), a0);
        a1 = fmaf(w, __builtin_amdgcn_cvt_f32_fp8(t[c], 1), a1);
    }
    store_nt_feat(dst, a0, a1);
}

// All 8 hash levels in ONE persistent launch, XCD-pinned: level = blockIdx&7,
// so with round-robin block->XCD dispatch each XCD's 4 MB L2 holds exactly
// ONE level's 4 MB fp8 table for the whole kernel. 4 pts/thread => 32
// table gathers in flight per thread.
__global__ void __launch_bounds__(256) enc_hash_all_kernel(
        const float* __restrict__ pts, int pbase, int npts,
        const ushort_t* __restrict__ tabq, unsigned hash_off0,
        HashScales hs,
        __hip_bfloat162* __restrict__ feats) {   // slab base (level 0)
    const int lev = blockIdx.x & 7;              // 0..7 -> level 4+lev
    const int bpl = blockIdx.x >> 3;             // block index within level
    const int tid = threadIdx.x;
    float scale = hs.s[0];
    #pragma unroll
    for (int k = 1; k < 8; ++k) if (lev == k) scale = hs.s[k];  // cselect x7
    const ushort_t* __restrict__ base =
        tabq + hash_off0 + ((unsigned)lev << 21);
    const unsigned m = (1u << 21) - 1u;
    __hip_bfloat162* __restrict__ slab = feats + (size_t)(4 + lev) * npts;

    const int stride = NBLK_PER_LEV * 1024;
    for (int p0 = bpl * 1024; p0 < npts; p0 += stride) {
        int  idx[4];
        bool val[4];
        HashPt hp[4];
        int  t[4][8];
        #pragma unroll
        for (int q = 0; q < 4; ++q) {
            int i = p0 + q * 256 + tid;
            val[q] = i < npts;
            idx[q] = val[q] ? i : npts - 1;
            hp[q]  = hash_addrs(pts, pbase + idx[q], scale, m);
            #pragma unroll
            for (int c = 0; c < 8; ++c) t[q][c] = (int)base[hp[q].h[c]];
        }
        #pragma unroll
        for (int q = 0; q < 4; ++q)
            if (val[q]) interp_store(t[q], hp[q], slab + idx[q]);
    }
}

// ---------------------------------------------------------------------------
// MFMA per-line MLP + weighted |op-gt| sum. One block (4 waves) per line.
// A = feats (16 pts x K32, features 24..31 zero), B = W1 bf16 (K32 x 16),
// 4 n-blocks cover the 64 hidden units. b1 is preloaded into the accumulator.
// Layouts (gfx950 16x16x32 bf16):
//   A: lane l holds A[l&15][(l>>4)*8 + i]           (i = 0..7)
//   B: lane l holds B[(l>>4)*8 + i][l&15]
//   D: lane l holds D[(l>>4)*4 + r][l&15]           (r = 0..3)
__global__ void __launch_bounds__(256) mlp_loss_mfma_kernel(
        const unsigned* __restrict__ feats, int npts,
        const float* __restrict__ gt, int line0,
        const float* __restrict__ w1, const float* __restrict__ b1,
        const float* __restrict__ w2, const float* __restrict__ b2,
        float* __restrict__ S) {
    const int line_local = blockIdx.x;
    const int tid  = threadIdx.x;
    const int wave = tid >> 6;
    const int lane = tid & 63;
    const int c = lane & 15;      // hidden col within 16 / A point row
    const int g = lane >> 4;      // k-group (0..3)

    // Loop-invariant B fragments: W1[k][64] f32 -> bf16, K padded 24->32.
    short8_t bfrag[4];
    #pragma unroll
    for (int nb = 0; nb < 4; ++nb) {
        #pragma unroll
        for (int i = 0; i < 8; ++i) {
            int k = g * 8 + i;
            float v = (k < 24) ? w1[k * 64 + nb * 16 + c] : 0.f;
            bfrag[nb][i] = (short)f32_to_bf16_bits(v);
        }
    }
    float b1v[4], w2v[4];
    #pragma unroll
    for (int nb = 0; nb < 4; ++nb) {
        b1v[nb] = b1[nb * 16 + c];
        w2v[nb] = w2[nb * 16 + c];
    }
    const float b2v = b2[0];

    const size_t lbase = (size_t)line_local * P_PTS;
    float lsum = 0.f;

    // 16 iterations x 4 waves x 16 points = 1024 >= 1000 (tail masked).
    for (int it = 0; it < 16; ++it) {
        const int base16 = it * 64 + wave * 16;
        // --- A fragment: point row = c, k = g*8 + i (2 bf16 per level slab)
        int prow = base16 + c;
        int pcl  = prow < P_PTS ? prow : P_PTS - 1;
        size_t pidx = lbase + (size_t)pcl;
        union { unsigned u[4]; short8_t v; } a;
        if (g < 3) {
            #pragma unroll
            for (int s = 0; s < 4; ++s)
                a.u[s] = feats[(size_t)(g * 4 + s) * npts + pidx];
        } else {
            a.u[0] = 0u; a.u[1] = 0u; a.u[2] = 0u; a.u[3] = 0u;
        }
        // --- layer 1: 4 MFMAs, accumulator seeded with b1
        f32x4 acc[4];
        #pragma unroll
        for (int nb = 0; nb < 4; ++nb) {
            f32x4 ci = {b1v[nb], b1v[nb], b1v[nb], b1v[nb]};
            acc[nb] = __builtin_amdgcn_mfma_f32_16x16x32_bf16(
                a.v, bfrag[nb], ci, 0, 0, 0);
        }
        // --- layer 2: relu + dot with w2, reduce across the 16-lane group
        float part[4];
        #pragma unroll
        for (int r = 0; r < 4; ++r) {
            float s = fmaxf(acc[0][r], 0.f) * w2v[0];
            s = fmaf(fmaxf(acc[1][r], 0.f), w2v[1], s);
            s = fmaf(fmaxf(acc[2][r], 0.f), w2v[2], s);
            s = fmaf(fmaxf(acc[3][r], 0.f), w2v[3], s);
            part[r] = s;
        }
        #pragma unroll
        for (int off = 1; off < 16; off <<= 1) {
            #pragma unroll
            for (int r = 0; r < 4; ++r)
                part[r] += __shfl_xor(part[r], off);
        }
        // lane c<4 owns point p = base16 + g*4 + c (exactly one lane/point)
        if (c < 4) {
            int p = base16 + g * 4 + c;
            if (p < P_PTS) {
                float op = part[c] + b2v;
                float gv = gt[(size_t)(line0 + line_local) * P_PTS + p];
                float cw = (p < 500) ? (float)(4.0 / 3.0) : (float)(2.0 / 3.0);
                lsum += fabsf(op - gv) * cw;
            }
        }
    }
    float tot = block_reduce_256(lsum);
    if (tid == 0) S[line0 + line_local] = tot;
}

// ---------------------------------------------------------------------------
// Fallback monolithic opacity kernel (R1 structure) if ws is too small.
__global__ void __launch_bounds__(256) opacity_mono_kernel(
        const float* __restrict__ pts, const float* __restrict__ gt,
        const float2* __restrict__ tab,
        const float* __restrict__ w1, const float* __restrict__ b1,
        const float* __restrict__ w2, const float* __restrict__ b2,
        float* __restrict__ S, Specs sp) {
    const int b = blockIdx.x;
    const int tid = threadIdx.x;
    float lsum = 0.f;
    for (int p = tid; p < P_PTS; p += 256) {
        const int i = b * P_PTS + p;
        float x0 = (pts[3 * i + 0] + 1.f) * 0.5f;
        float x1 = (pts[3 * i + 1] + 1.f) * 0.5f;
        float x2 = (pts[3 * i + 2] + 1.f) * 0.5f;
        float feat[24];
        #pragma unroll
        for (int l = 0; l < NLEV; ++l) {
            const LevelSpec L = sp.L[l];
            float p0 = x0 * L.scale + 0.5f;
            float p1 = x1 * L.scale + 0.5f;
            float p2 = x2 * L.scale + 0.5f;
            float f0 = floorf(p0), f1 = floorf(p1), f2 = floorf(p2);
            float r0 = p0 - f0, r1 = p1 - f1, r2 = p2 - f2;
            float u0 = 1.f - r0, u1 = 1.f - r1, u2 = 1.f - r2;
            unsigned g0 = (unsigned)f0, g1 = (unsigned)f1, g2 = (unsigned)f2;
            float a0 = 0.f, a1 = 0.f;
            if (l >= 4) {
                unsigned y0 = g1 * 2654435761u, y1 = y0 + 2654435761u;
                unsigned z0 = g2 * 805459861u,  z1 = z0 + 805459861u;
                unsigned m = L.mask;
                #pragma unroll
                for (int c = 0; c < 8; ++c) {
                    unsigned h = (g0 + ((c & 1) ? 1u : 0u))
                               ^ ((c & 2) ? y1 : y0) ^ ((c & 4) ? z1 : z0);
                    float2 t = tab[L.off + (h & m)];
                    float w = ((c & 1) ? r0 : u0) * ((c & 2) ? r1 : u1)
                            * ((c & 4) ? r2 : u2);
                    a0 = fmaf(w, t.x, a0); a1 = fmaf(w, t.y, a1);
                }
            } else {
                unsigned R = L.R, R2 = R * R;
                unsigned y0 = g1 * R, y1 = y0 + R;
                unsigned z0 = g2 * R2, z1 = z0 + R2;
                #pragma unroll
                for (int c = 0; c < 8; ++c) {
                    unsigned idx = (g0 + ((c & 1) ? 1u : 0u))
                                 + ((c & 2) ? y1 : y0) + ((c & 4) ? z1 : z0);
                    float2 t = tab[L.off + idx];
                    float w = ((c & 1) ? r0 : u0) * ((c & 2) ? r1 : u1)
                            * ((c & 4) ? r2 : u2);
                    a0 = fmaf(w, t.x, a0); a1 = fmaf(w, t.y, a1);
                }
            }
            feat[2 * l] = a0; feat[2 * l + 1] = a1;
        }
        float op = mlp_24_64_1(feat, w1, b1, w2, b2);
        float cw = (p < 500) ? (float)(4.0 / 3.0) : (float)(2.0 / 3.0);
        lsum += fabsf(op - gt[i]) * cw;
    }
    float tot = block_reduce_256(lsum);
    if (tid == 0) S[b] = tot;
}

// Confidence (D=2, tiny) + final reduction: unchanged (f32 table).
__global__ void __launch_bounds__(256) conf_kernel(
        const float* __restrict__ line, const float2* __restrict__ tab,
        const float* __restrict__ w1, const float* __restrict__ b1,
        const float* __restrict__ w2, const float* __restrict__ b2,
        const float* __restrict__ S, float* __restrict__ partial, Specs sp) {
    const int b = blockIdx.x * 256 + threadIdx.x;
    float x0 = (line[2 * b + 0] + 1.f) * 0.5f;
    float x1 = (line[2 * b + 1] + 1.f) * 0.5f;
    float feat[24];
    #pragma unroll
    for (int l = 0; l < NLEV; ++l) {
        const unsigned off = sp.L[l].off;
        const float scale = sp.L[l].scale;
        float p0 = x0 * scale + 0.5f;
        float p1 = x1 * scale + 0.5f;
        float f0 = floorf(p0), f1 = floorf(p1);
        float r0 = p0 - f0, r1 = p1 - f1;
        float u0 = 1.f - r0, u1 = 1.f - r1;
        unsigned g0 = (unsigned)f0, g1 = (unsigned)f1;
        unsigned idx0, idx1, idx2, idx3;
        if (l >= 8) {
            const unsigned mask = sp.L[l].mask;
            unsigned a1 = g1 * 2654435761u, bb1 = a1 + 2654435761u;
            idx0 = (g0 ^ a1) & mask;
            idx1 = ((g0 + 1u) ^ a1) & mask;
            idx2 = (g0 ^ bb1) & mask;
            idx3 = ((g0 + 1u) ^ bb1) & mask;
        } else {
            const unsigned R = sp.L[l].R;
            unsigned a1 = g1 * R, bb1 = a1 + R;
            idx0 = g0 + a1; idx1 = g0 + 1u + a1;
            idx2 = g0 + bb1; idx3 = g0 + 1u + bb1;
        }
        float2 t0 = tab[off + idx0], t1 = tab[off + idx1];
        float2 t2 = tab[off + idx2], t3 = tab[off + idx3];
        float w0 = u0 * u1, w1c = r0 * u1, w2c = u0 * r1, w3 = r0 * r1;
        feat[2 * l]     = w0 * t0.x + w1c * t1.x + w2c * t2.x + w3 * t3.x;
        feat[2 * l + 1] = w0 * t0.y + w1c * t1.y + w2c * t2.y + w3 * t3.y;
    }
    float conf = mlp_24_64_1(feat, w1, b1, w2, b2);
    float term = expf(-conf) * (S[b] * (1.0f / (float)P_PTS)) + conf;
    float tot = block_reduce_256(term);
    if (threadIdx.x == 0) partial[blockIdx.x] = tot;
}

__global__ void final_kernel(const float* __restrict__ partial,
                             float* __restrict__ out) {
    if (threadIdx.x == 0) {
        float s = 0.f;
        for (int i = 0; i < 16; ++i) s += partial[i];
        out[0] = s * (1.0f / (float)B_LINES);
    }
}

// ---------------------------------------------------------------------------

extern "C" void kernel_launch(void* const* d_in, const int* in_sizes, int n_in,
                              void* d_out, int out_size, void* d_ws, size_t ws_size,
                              hipStream_t stream) {
    const float* line    = (const float*)d_in[0];
    const float* pts     = (const float*)d_in[1];
    const float* gt      = (const float*)d_in[2];
    const float* table_c = (const float*)d_in[3];
    const float* w1_c    = (const float*)d_in[4];
    const float* b1_c    = (const float*)d_in[5];
    const float* w2_c    = (const float*)d_in[6];
    const float* b2_c    = (const float*)d_in[7];
    const float* table_o = (const float*)d_in[8];
    const float* w1_o    = (const float*)d_in[9];
    const float* b1_o    = (const float*)d_in[10];
    const float* w2_o    = (const float*)d_in[11];
    const float* b2_o    = (const float*)d_in[12];
    (void)in_sizes; (void)n_in; (void)out_size;

    Specs sp3, sp2;
    unsigned tot3 = compute_specs(3, &sp3);
    compute_specs(2, &sp2);

    // ws layout: [fp8 table][S 4096][partial 16][feat slabs]
    size_t tabB = (((size_t)tot3 * 2) + 255) & ~(size_t)255;
    size_t head = tabB + (size_t)B_LINES * 4 + 64;
    head = (head + 63) & ~(size_t)63;
    long max_lines = 0;
    if (ws_size > head + 64)
        max_lines = (long)((ws_size - head - 64) / ((size_t)P_PTS * 12 * 4));

    float* S       = (float*)((char*)d_ws + tabB);
    float* partial = S + B_LINES;

    if (max_lines >= 64) {
        // Phased fp8 path.
        ushort_t* tabq = (ushort_t*)d_ws;
        __hip_bfloat162* featbuf = (__hip_bfloat162*)((char*)d_ws + head);

        int chunk_lines = (int)(max_lines < B_LINES ? max_lines : B_LINES);
        int nch = (B_LINES + chunk_lines - 1) / chunk_lines;

        HashScales hs;
        for (int k = 0; k < 8; ++k) hs.s[k] = sp3.L[4 + k].scale;
        const unsigned hash_off0 = sp3.L[4].off;

        convert_kernel<<<((int)tot3 + 255) / 256, 256, 0, stream>>>(
            (const float2*)table_o, tabq, (int)tot3);

        for (int ch = 0; ch < nch; ++ch) {
            int line0 = ch * chunk_lines;
            int lines = B_LINES - line0 < chunk_lines ? B_LINES - line0
                                                      : chunk_lines;
            int npts = lines * P_PTS;
            int pbase = line0 * P_PTS;
            int nblk = (npts + 255) / 256;
            enc_dense_kernel<<<nblk, 256, 0, stream>>>(
                pts, pbase, npts, tabq, featbuf, sp3);
            enc_hash_all_kernel<<<NBLK_PER_LEV * 8, 256, 0, stream>>>(
                pts, pbase, npts, tabq, hash_off0, hs, featbuf);
            mlp_loss_mfma_kernel<<<lines, 256, 0, stream>>>(
                (const unsigned*)featbuf, npts, gt, line0,
                w1_o, b1_o, w2_o, b2_o, S);
        }
    } else {
        // Fallback: monolithic f32 path (needs only S+partial in ws).
        opacity_mono_kernel<<<B_LINES, 256, 0, stream>>>(
            pts, gt, (const float2*)table_o, w1_o, b1_o, w2_o, b2_o, S, sp3);
    }

    conf_kernel<<<16, 256, 0, stream>>>(
        line, (const float2*)table_c, w1_c, b1_c, w2_c, b2_c, S, partial, sp2);
    final_kernel<<<1, 64, 0, stream>>>(partial, (float*)d_out);
}

// Round 5
// 1361.053 us; speedup vs baseline: 1.4485x; 1.0361x over previous
//
#include <hip/hip_runtime.h>
#include <hip/hip_bf16.h>
#include <math.h>

#define NLEV 12
#define B_LINES 4096
#define P_PTS 1000
#define FP8_SCALE 65536.0f
#define FP8_ISCALE (1.0f / 65536.0f)
#define NBLK_PER_LEV 256

typedef unsigned short ushort_t;
typedef __attribute__((ext_vector_type(8))) short short8_t;   // 8 bf16 (4 VGPRs)
typedef __attribute__((ext_vector_type(4))) float f32x4;

// Per-level table layout, mirrors _level_specs() exactly.
struct LevelSpec {
    unsigned off;    // entry offset into table (rows of 2 features)
    unsigned mask;   // params-1 (power-of-2 for hash levels)
    float    scale;  // BASE_RES * f^l - 1
    unsigned R;      // res + 1 (dense stride base)
};
struct Specs { LevelSpec L[NLEV]; };
struct HashScales { float s[8]; };   // scales for levels 4..11

static unsigned compute_specs(int D, Specs* sp) {
    double f = pow(8192.0 / 16.0, 1.0 / 11.0);
    unsigned offset = 0;
    for (int l = 0; l < NLEV; ++l) {
        double scale = 16.0 * pow(f, (double)l) - 1.0;
        int res = (int)ceil(scale) + 1;
        unsigned long long dense = 1ull;
        for (int d = 0; d < D; ++d) dense *= (unsigned long long)(res + 1);
        unsigned long long params = dense > (1ull << 21) ? (1ull << 21) : dense;
        params = ((params + 7ull) / 8ull) * 8ull;
        sp->L[l].off   = offset;
        sp->L[l].mask  = (unsigned)params - 1u;
        sp->L[l].scale = (float)scale;
        sp->L[l].R     = (unsigned)(res + 1);
        offset += (unsigned)params;
    }
    return offset;  // total entries
}

// ---------------------------------------------------------------------------

__device__ __forceinline__ float block_reduce_256(float v) {
    __shared__ float red[256];
    int tid = threadIdx.x;
    red[tid] = v;
    __syncthreads();
    #pragma unroll
    for (int s = 128; s >= 1; s >>= 1) {
        if (tid < s) red[tid] += red[tid + s];
        __syncthreads();
    }
    return red[0];
}

__device__ __forceinline__ unsigned short f32_to_bf16_bits(float f) {
    unsigned u = __float_as_uint(f);
    unsigned r = (u + 0x7fffu + ((u >> 16) & 1u)) >> 16;   // RNE
    return (unsigned short)r;
}

// bf16x2 pack + non-temporal store (evict-first: don't displace table lines).
__device__ __forceinline__ void store_nt_feat(__hip_bfloat162* p,
                                              float a0, float a1) {
    union { __hip_bfloat162 b; unsigned u; } cv;
    cv.b.x = __float2bfloat16(a0 * FP8_ISCALE);
    cv.b.y = __float2bfloat16(a1 * FP8_ISCALE);
    __builtin_nontemporal_store(cv.u, (unsigned*)p);
}

// Aligned-pair table read: one u32 covers entries {H&~1, (H&~1)+1}; select
// the 2-byte entry by H&1. Two x-corners with even g0 share the SAME u32
// address -> L1/MSHR merges them into one L2 transaction (the hash uses
// PRIME0=1, so corner pair = {H, H^1} when g0 even).
__device__ __forceinline__ int pair_entry(const ushort_t* __restrict__ base,
                                          unsigned H) {
    unsigned w = *(const unsigned*)(base + (H & ~1u));
    return (int)((w >> ((H & 1u) << 4)) & 0xffffu);
}

// MLP 24 -> 64(relu) -> 1; weights wave-uniform -> s_load + v_fmac.
// (used by the fallback mono path and conf path)
__device__ __forceinline__ float mlp_24_64_1(const float feat[24],
        const float* __restrict__ w1, const float* __restrict__ b1,
        const float* __restrict__ w2, const float* __restrict__ b2) {
    float o = b2[0];
    #pragma unroll
    for (int half = 0; half < 2; ++half) {
        float h[32];
        #pragma unroll
        for (int j = 0; j < 32; ++j) h[j] = b1[half * 32 + j];
        #pragma unroll
        for (int k = 0; k < 24; ++k) {
            float fv = feat[k];
            #pragma unroll
            for (int j = 0; j < 32; ++j)
                h[j] = fmaf(fv, w1[k * 64 + half * 32 + j], h[j]);
        }
        #pragma unroll
        for (int j = 0; j < 32; ++j)
            o = fmaf(fmaxf(h[j], 0.f), w2[half * 32 + j], o);
    }
    return o;
}

// ---------------------------------------------------------------------------
// fp8 table conversion: one row (2 features) -> 2 bytes, scaled by 2^16.
__global__ void __launch_bounds__(256) convert_kernel(
        const float2* __restrict__ in, ushort_t* __restrict__ out, int n) {
    int i = blockIdx.x * 256 + threadIdx.x;
    if (i >= n) return;
    float2 v;
    v.x = __builtin_nontemporal_load(&in[i].x);
    v.y = __builtin_nontemporal_load(&in[i].y);
    int p = __builtin_amdgcn_cvt_pk_fp8_f32(v.x * FP8_SCALE, v.y * FP8_SCALE,
                                            0, false);
    __builtin_nontemporal_store((ushort_t)(p & 0xffff), &out[i]);
}

// Dense levels 0..3 (combined fp8 footprint ~1.8 MB: L2-resident).
// Plain (cached) pts loads warm L3 for the hash kernel. Dense corners
// (idx, idx+1) are ALWAYS adjacent -> pair loads halve L2 transactions.
__global__ void __launch_bounds__(256) enc_dense_kernel(
        const float* __restrict__ pts, int pbase, int npts,
        const ushort_t* __restrict__ tabq,
        __hip_bfloat162* __restrict__ feats,   // 12 slabs of npts
        Specs sp) {
    int i = blockIdx.x * 256 + threadIdx.x;
    if (i >= npts) return;
    int gp = pbase + i;
    float x0 = (pts[3 * gp + 0] + 1.f) * 0.5f;
    float x1 = (pts[3 * gp + 1] + 1.f) * 0.5f;
    float x2 = (pts[3 * gp + 2] + 1.f) * 0.5f;
    #pragma unroll
    for (int l = 0; l < 4; ++l) {
        const LevelSpec L = sp.L[l];
        float p0 = x0 * L.scale + 0.5f;
        float p1 = x1 * L.scale + 0.5f;
        float p2 = x2 * L.scale + 0.5f;
        float f0 = floorf(p0), f1 = floorf(p1), f2 = floorf(p2);
        float r0 = p0 - f0, r1 = p1 - f1, r2 = p2 - f2;
        float u0 = 1.f - r0, u1 = 1.f - r1, u2 = 1.f - r2;
        unsigned g0 = (unsigned)f0, g1 = (unsigned)f1, g2 = (unsigned)f2;
        const ushort_t* __restrict__ base = tabq + L.off;
        unsigned R = L.R, R2 = R * R;
        unsigned y0 = g1 * R, y1 = y0 + R;
        unsigned z0 = g2 * R2, z1 = z0 + R2;
        int t[8];
        #pragma unroll
        for (int cz = 0; cz < 4; ++cz) {
            unsigned idx0 = g0 + ((cz & 1) ? y1 : y0) + ((cz & 2) ? z1 : z0);
            t[2 * cz]     = pair_entry(base, idx0);
            t[2 * cz + 1] = pair_entry(base, idx0 + 1u);
        }
        float a0 = 0.f, a1 = 0.f;
        #pragma unroll
        for (int c = 0; c < 8; ++c) {
            float w = ((c & 1) ? r0 : u0) * ((c & 2) ? r1 : u1)
                    * ((c & 4) ? r2 : u2);
            a0 = fmaf(w, __builtin_amdgcn_cvt_f32_fp8(t[c], 0), a0);
            a1 = fmaf(w, __builtin_amdgcn_cvt_f32_fp8(t[c], 1), a1);
        }
        store_nt_feat(&feats[(size_t)l * npts + i], a0, a1);
    }
}

// Per-point hash addresses + fractional weights (plain cached pts loads:
// pts sit in L3 after the dense pass).
struct HashPt { unsigned h[8]; float r0, r1, r2; };

__device__ __forceinline__ HashPt hash_addrs(
        const float* __restrict__ pts, int gp, float scale, unsigned m) {
    float x0 = (pts[3 * gp + 0] + 1.f) * 0.5f;
    float x1 = (pts[3 * gp + 1] + 1.f) * 0.5f;
    float x2 = (pts[3 * gp + 2] + 1.f) * 0.5f;
    float p0 = x0 * scale + 0.5f;
    float p1 = x1 * scale + 0.5f;
    float p2 = x2 * scale + 0.5f;
    float f0 = floorf(p0), f1 = floorf(p1), f2 = floorf(p2);
    HashPt o;
    o.r0 = p0 - f0; o.r1 = p1 - f1; o.r2 = p2 - f2;
    unsigned g0 = (unsigned)f0, g1 = (unsigned)f1, g2 = (unsigned)f2;
    unsigned y0 = g1 * 2654435761u, y1 = y0 + 2654435761u;
    unsigned z0 = g2 * 805459861u,  z1 = z0 + 805459861u;
    #pragma unroll
    for (int c = 0; c < 8; ++c) {
        unsigned h = (g0 + ((c & 1) ? 1u : 0u))
                   ^ ((c & 2) ? y1 : y0) ^ ((c & 4) ? z1 : z0);
        o.h[c] = h & m;
    }
    return o;
}

__device__ __forceinline__ void interp_store(
        const int t[8], const HashPt& hp, __hip_bfloat162* dst) {
    float u0 = 1.f - hp.r0, u1 = 1.f - hp.r1, u2 = 1.f - hp.r2;
    float a0 = 0.f, a1 = 0.f;
    #pragma unroll
    for (int c = 0; c < 8; ++c) {
        float w = ((c & 1) ? hp.r0 : u0) * ((c & 2) ? hp.r1 : u1)
                * ((c & 4) ? hp.r2 : u2);
        a0 = fmaf(w, __builtin_amdgcn_cvt_f32_fp8(t[c], 0), a0);
        a1 = fmaf(w, __builtin_amdgcn_cvt_f32_fp8(t[c], 1), a1);
    }
    store_nt_feat(dst, a0, a1);
}

// All 8 hash levels in ONE persistent launch, XCD-pinned: level = blockIdx&7,
// so with round-robin block->XCD dispatch each XCD's 4 MB L2 holds exactly
// ONE level's 4 MB fp8 table for the whole kernel. 4 pts/thread. Pair loads:
// even-g0 x-corner pairs merge to one L2 transaction (avg 6/pt vs 8/pt).
__global__ void __launch_bounds__(256) enc_hash_all_kernel(
        const float* __restrict__ pts, int pbase, int npts,
        const ushort_t* __restrict__ tabq, unsigned hash_off0,
        HashScales hs,
        __hip_bfloat162* __restrict__ feats) {   // slab base (level 0)
    const int lev = blockIdx.x & 7;              // 0..7 -> level 4+lev
    const int bpl = blockIdx.x >> 3;             // block index within level
    const int tid = threadIdx.x;
    float scale = hs.s[0];
    #pragma unroll
    for (int k = 1; k < 8; ++k) if (lev == k) scale = hs.s[k];  // cselect x7
    const ushort_t* __restrict__ base =
        tabq + hash_off0 + ((unsigned)lev << 21);
    const unsigned m = (1u << 21) - 1u;
    __hip_bfloat162* __restrict__ slab = feats + (size_t)(4 + lev) * npts;

    const int stride = NBLK_PER_LEV * 1024;
    for (int p0 = bpl * 1024; p0 < npts; p0 += stride) {
        int  idx[4];
        bool val[4];
        HashPt hp[4];
        int  t[4][8];
        #pragma unroll
        for (int q = 0; q < 4; ++q) {
            int i = p0 + q * 256 + tid;
            val[q] = i < npts;
            idx[q] = val[q] ? i : npts - 1;
            hp[q]  = hash_addrs(pts, pbase + idx[q], scale, m);
            #pragma unroll
            for (int c = 0; c < 8; ++c)
                t[q][c] = pair_entry(base, hp[q].h[c]);
        }
        #pragma unroll
        for (int q = 0; q < 4; ++q)
            if (val[q]) interp_store(t[q], hp[q], slab + idx[q]);
    }
}

// ---------------------------------------------------------------------------
// MFMA per-line MLP + weighted |op-gt| sum. One block (4 waves) per line.
// A = feats (16 pts x K32, features 24..31 zero), B = W1 bf16 (K32 x 16),
// 4 n-blocks cover the 64 hidden units. b1 is preloaded into the accumulator.
// Layouts (gfx950 16x16x32 bf16):
//   A: lane l holds A[l&15][(l>>4)*8 + i]           (i = 0..7)
//   B: lane l holds B[(l>>4)*8 + i][l&15]
//   D: lane l holds D[(l>>4)*4 + r][l&15]           (r = 0..3)
__global__ void __launch_bounds__(256) mlp_loss_mfma_kernel(
        const unsigned* __restrict__ feats, int npts,
        const float* __restrict__ gt, int line0,
        const float* __restrict__ w1, const float* __restrict__ b1,
        const float* __restrict__ w2, const float* __restrict__ b2,
        float* __restrict__ S) {
    const int line_local = blockIdx.x;
    const int tid  = threadIdx.x;
    const int wave = tid >> 6;
    const int lane = tid & 63;
    const int c = lane & 15;      // hidden col within 16 / A point row
    const int g = lane >> 4;      // k-group (0..3)

    // Loop-invariant B fragments: W1[k][64] f32 -> bf16, K padded 24->32.
    short8_t bfrag[4];
    #pragma unroll
    for (int nb = 0; nb < 4; ++nb) {
        #pragma unroll
        for (int i = 0; i < 8; ++i) {
            int k = g * 8 + i;
            float v = (k < 24) ? w1[k * 64 + nb * 16 + c] : 0.f;
            bfrag[nb][i] = (short)f32_to_bf16_bits(v);
        }
    }
    float b1v[4], w2v[4];
    #pragma unroll
    for (int nb = 0; nb < 4; ++nb) {
        b1v[nb] = b1[nb * 16 + c];
        w2v[nb] = w2[nb * 16 + c];
    }
    const float b2v = b2[0];

    const size_t lbase = (size_t)line_local * P_PTS;
    float lsum = 0.f;

    // 16 iterations x 4 waves x 16 points = 1024 >= 1000 (tail masked).
    for (int it = 0; it < 16; ++it) {
        const int base16 = it * 64 + wave * 16;
        // --- A fragment: point row = c, k = g*8 + i (2 bf16 per level slab)
        int prow = base16 + c;
        int pcl  = prow < P_PTS ? prow : P_PTS - 1;
        size_t pidx = lbase + (size_t)pcl;
        union { unsigned u[4]; short8_t v; } a;
        if (g < 3) {
            #pragma unroll
            for (int s = 0; s < 4; ++s)
                a.u[s] = feats[(size_t)(g * 4 + s) * npts + pidx];
        } else {
            a.u[0] = 0u; a.u[1] = 0u; a.u[2] = 0u; a.u[3] = 0u;
        }
        // --- layer 1: 4 MFMAs, accumulator seeded with b1
        f32x4 acc[4];
        #pragma unroll
        for (int nb = 0; nb < 4; ++nb) {
            f32x4 ci = {b1v[nb], b1v[nb], b1v[nb], b1v[nb]};
            acc[nb] = __builtin_amdgcn_mfma_f32_16x16x32_bf16(
                a.v, bfrag[nb], ci, 0, 0, 0);
        }
        // --- layer 2: relu + dot with w2, reduce across the 16-lane group
        float part[4];
        #pragma unroll
        for (int r = 0; r < 4; ++r) {
            float s = fmaxf(acc[0][r], 0.f) * w2v[0];
            s = fmaf(fmaxf(acc[1][r], 0.f), w2v[1], s);
            s = fmaf(fmaxf(acc[2][r], 0.f), w2v[2], s);
            s = fmaf(fmaxf(acc[3][r], 0.f), w2v[3], s);
            part[r] = s;
        }
        #pragma unroll
        for (int off = 1; off < 16; off <<= 1) {
            #pragma unroll
            for (int r = 0; r < 4; ++r)
                part[r] += __shfl_xor(part[r], off);
        }
        // lane c<4 owns point p = base16 + g*4 + c (exactly one lane/point)
        if (c < 4) {
            int p = base16 + g * 4 + c;
            if (p < P_PTS) {
                float op = part[c] + b2v;
                float gv = gt[(size_t)(line0 + line_local) * P_PTS + p];
                float cw = (p < 500) ? (float)(4.0 / 3.0) : (float)(2.0 / 3.0);
                lsum += fabsf(op - gv) * cw;
            }
        }
    }
    float tot = block_reduce_256(lsum);
    if (tid == 0) S[line0 + line_local] = tot;
}

// ---------------------------------------------------------------------------
// Fallback monolithic opacity kernel (R1 structure) if ws is too small.
__global__ void __launch_bounds__(256) opacity_mono_kernel(
        const float* __restrict__ pts, const float* __restrict__ gt,
        const float2* __restrict__ tab,
        const float* __restrict__ w1, const float* __restrict__ b1,
        const float* __restrict__ w2, const float* __restrict__ b2,
        float* __restrict__ S, Specs sp) {
    const int b = blockIdx.x;
    const int tid = threadIdx.x;
    float lsum = 0.f;
    for (int p = tid; p < P_PTS; p += 256) {
        const int i = b * P_PTS + p;
        float x0 = (pts[3 * i + 0] + 1.f) * 0.5f;
        float x1 = (pts[3 * i + 1] + 1.f) * 0.5f;
        float x2 = (pts[3 * i + 2] + 1.f) * 0.5f;
        float feat[24];
        #pragma unroll
        for (int l = 0; l < NLEV; ++l) {
            const LevelSpec L = sp.L[l];
            float p0 = x0 * L.scale + 0.5f;
            float p1 = x1 * L.scale + 0.5f;
            float p2 = x2 * L.scale + 0.5f;
            float f0 = floorf(p0), f1 = floorf(p1), f2 = floorf(p2);
            float r0 = p0 - f0, r1 = p1 - f1, r2 = p2 - f2;
            float u0 = 1.f - r0, u1 = 1.f - r1, u2 = 1.f - r2;
            unsigned g0 = (unsigned)f0, g1 = (unsigned)f1, g2 = (unsigned)f2;
            float a0 = 0.f, a1 = 0.f;
            if (l >= 4) {
                unsigned y0 = g1 * 2654435761u, y1 = y0 + 2654435761u;
                unsigned z0 = g2 * 805459861u,  z1 = z0 + 805459861u;
                unsigned m = L.mask;
                #pragma unroll
                for (int c = 0; c < 8; ++c) {
                    unsigned h = (g0 + ((c & 1) ? 1u : 0u))
                               ^ ((c & 2) ? y1 : y0) ^ ((c & 4) ? z1 : z0);
                    float2 t = tab[L.off + (h & m)];
                    float w = ((c & 1) ? r0 : u0) * ((c & 2) ? r1 : u1)
                            * ((c & 4) ? r2 : u2);
                    a0 = fmaf(w, t.x, a0); a1 = fmaf(w, t.y, a1);
                }
            } else {
                unsigned R = L.R, R2 = R * R;
                unsigned y0 = g1 * R, y1 = y0 + R;
                unsigned z0 = g2 * R2, z1 = z0 + R2;
                #pragma unroll
                for (int c = 0; c < 8; ++c) {
                    unsigned idx = (g0 + ((c & 1) ? 1u : 0u))
                                 + ((c & 2) ? y1 : y0) + ((c & 4) ? z1 : z0);
                    float2 t = tab[L.off + idx];
                    float w = ((c & 1) ? r0 : u0) * ((c & 2) ? r1 : u1)
                            * ((c & 4) ? r2 : u2);
                    a0 = fmaf(w, t.x, a0); a1 = fmaf(w, t.y, a1);
                }
            }
            feat[2 * l] = a0; feat[2 * l + 1] = a1;
        }
        float op = mlp_24_64_1(feat, w1, b1, w2, b2);
        float cw = (p < 500) ? (float)(4.0 / 3.0) : (float)(2.0 / 3.0);
        lsum += fabsf(op - gt[i]) * cw;
    }
    float tot = block_reduce_256(lsum);
    if (tid == 0) S[b] = tot;
}

// Confidence (D=2, tiny) + final reduction: unchanged (f32 table).
__global__ void __launch_bounds__(256) conf_kernel(
        const float* __restrict__ line, const float2* __restrict__ tab,
        const float* __restrict__ w1, const float* __restrict__ b1,
        const float* __restrict__ w2, const float* __restrict__ b2,
        const float* __restrict__ S, float* __restrict__ partial, Specs sp) {
    const int b = blockIdx.x * 256 + threadIdx.x;
    float x0 = (line[2 * b + 0] + 1.f) * 0.5f;
    float x1 = (line[2 * b + 1] + 1.f) * 0.5f;
    float feat[24];
    #pragma unroll
    for (int l = 0; l < NLEV; ++l) {
        const unsigned off = sp.L[l].off;
        const float scale = sp.L[l].scale;
        float p0 = x0 * scale + 0.5f;
        float p1 = x1 * scale + 0.5f;
        float f0 = floorf(p0), f1 = floorf(p1);
        float r0 = p0 - f0, r1 = p1 - f1;
        float u0 = 1.f - r0, u1 = 1.f - r1;
        unsigned g0 = (unsigned)f0, g1 = (unsigned)f1;
        unsigned idx0, idx1, idx2, idx3;
        if (l >= 8) {
            const unsigned mask = sp.L[l].mask;
            unsigned a1 = g1 * 2654435761u, bb1 = a1 + 2654435761u;
            idx0 = (g0 ^ a1) & mask;
            idx1 = ((g0 + 1u) ^ a1) & mask;
            idx2 = (g0 ^ bb1) & mask;
            idx3 = ((g0 + 1u) ^ bb1) & mask;
        } else {
            const unsigned R = sp.L[l].R;
            unsigned a1 = g1 * R, bb1 = a1 + R;
            idx0 = g0 + a1; idx1 = g0 + 1u + a1;
            idx2 = g0 + bb1; idx3 = g0 + 1u + bb1;
        }
        float2 t0 = tab[off + idx0], t1 = tab[off + idx1];
        float2 t2 = tab[off + idx2], t3 = tab[off + idx3];
        float w0 = u0 * u1, w1c = r0 * u1, w2c = u0 * r1, w3 = r0 * r1;
        feat[2 * l]     = w0 * t0.x + w1c * t1.x + w2c * t2.x + w3 * t3.x;
        feat[2 * l + 1] = w0 * t0.y + w1c * t1.y + w2c * t2.y + w3 * t3.y;
    }
    float conf = mlp_24_64_1(feat, w1, b1, w2, b2);
    float term = expf(-conf) * (S[b] * (1.0f / (float)P_PTS)) + conf;
    float tot = block_reduce_256(term);
    if (threadIdx.x == 0) partial[blockIdx.x] = tot;
}

__global__ void final_kernel(const float* __restrict__ partial,
                             float* __restrict__ out) {
    if (threadIdx.x == 0) {
        float s = 0.f;
        for (int i = 0; i < 16; ++i) s += partial[i];
        out[0] = s * (1.0f / (float)B_LINES);
    }
}

// ---------------------------------------------------------------------------

extern "C" void kernel_launch(void* const* d_in, const int* in_sizes, int n_in,
                              void* d_out, int out_size, void* d_ws, size_t ws_size,
                              hipStream_t stream) {
    const float* line    = (const float*)d_in[0];
    const float* pts     = (const float*)d_in[1];
    const float* gt      = (const float*)d_in[2];
    const float* table_c = (const float*)d_in[3];
    const float* w1_c    = (const float*)d_in[4];
    const float* b1_c    = (const float*)d_in[5];
    const float* w2_c    = (const float*)d_in[6];
    const float* b2_c    = (const float*)d_in[7];
    const float* table_o = (const float*)d_in[8];
    const float* w1_o    = (const float*)d_in[9];
    const float* b1_o    = (const float*)d_in[10];
    const float* w2_o    = (const float*)d_in[11];
    const float* b2_o    = (const float*)d_in[12];
    (void)in_sizes; (void)n_in; (void)out_size;

    Specs sp3, sp2;
    unsigned tot3 = compute_specs(3, &sp3);
    compute_specs(2, &sp2);

    // ws layout: [fp8 table][S 4096][partial 16][feat slabs]
    size_t tabB = (((size_t)tot3 * 2) + 255) & ~(size_t)255;
    size_t head = tabB + (size_t)B_LINES * 4 + 64;
    head = (head + 63) & ~(size_t)63;
    long max_lines = 0;
    if (ws_size > head + 64)
        max_lines = (long)((ws_size - head - 64) / ((size_t)P_PTS * 12 * 4));

    float* S       = (float*)((char*)d_ws + tabB);
    float* partial = S + B_LINES;

    if (max_lines >= 64) {
        // Phased fp8 path.
        ushort_t* tabq = (ushort_t*)d_ws;
        __hip_bfloat162* featbuf = (__hip_bfloat162*)((char*)d_ws + head);

        int chunk_lines = (int)(max_lines < B_LINES ? max_lines : B_LINES);
        int nch = (B_LINES + chunk_lines - 1) / chunk_lines;

        HashScales hs;
        for (int k = 0; k < 8; ++k) hs.s[k] = sp3.L[4 + k].scale;
        const unsigned hash_off0 = sp3.L[4].off;

        convert_kernel<<<((int)tot3 + 255) / 256, 256, 0, stream>>>(
            (const float2*)table_o, tabq, (int)tot3);

        for (int ch = 0; ch < nch; ++ch) {
            int line0 = ch * chunk_lines;
            int lines = B_LINES - line0 < chunk_lines ? B_LINES - line0
                                                      : chunk_lines;
            int npts = lines * P_PTS;
            int pbase = line0 * P_PTS;
            int nblk = (npts + 255) / 256;
            enc_dense_kernel<<<nblk, 256, 0, stream>>>(
                pts, pbase, npts, tabq, featbuf, sp3);
            enc_hash_all_kernel<<<NBLK_PER_LEV * 8, 256, 0, stream>>>(
                pts, pbase, npts, tabq, hash_off0, hs, featbuf);
            mlp_loss_mfma_kernel<<<lines, 256, 0, stream>>>(
                (const unsigned*)featbuf, npts, gt, line0,
                w1_o, b1_o, w2_o, b2_o, S);
        }
    } else {
        // Fallback: monolithic f32 path (needs only S+partial in ws).
        opacity_mono_kernel<<<B_LINES, 256, 0, stream>>>(
            pts, gt, (const float2*)table_o, w1_o, b1_o, w2_o, b2_o, S, sp3);
    }

    conf_kernel<<<16, 256, 0, stream>>>(
        line, (const float2*)table_c, w1_c, b1_c, w2_c, b2_c, S, partial, sp2);
    final_kernel<<<1, 64, 0, stream>>>(partial, (float*)d_out);
}